// Round 15
// baseline (336.744 us; speedup 1.0000x reference)
//
#include <hip/hip_runtime.h>
#include <hip/hip_bf16.h>
#include <float.h>

#define BSZ 16384
#define NCODES 1024
#define QD 2048
#define NCHUNK 64   // BSZ / 256
#define NCOLG 16    // 8 col-blocks x 2 wc-waves

typedef _Float16 f16x8 __attribute__((ext_vector_type(8)));
typedef _Float16 f16x4 __attribute__((ext_vector_type(4)));
typedef float f32x4 __attribute__((ext_vector_type(4)));

static __device__ __forceinline__ float one_minus_decay() { return (float)(1.0 - 0.99); }

static __device__ __forceinline__ void async_copy16(const void* src, void* lds) {
    __builtin_amdgcn_global_load_lds((const __attribute__((address_space(1))) void*)src,
                                     (__attribute__((address_space(3))) void*)lds, 16, 0, 0);
}

// ---------------- K1a: unified prep -- split EVERY row (ctx then q) to f16 hi/lo
// + its squared norm. One row per block; same cvt math as always (bit-identical).
__global__ void k_prep_all(const float* __restrict__ ctx, const float* __restrict__ q,
                           _Float16* __restrict__ gh, _Float16* __restrict__ gl,
                           float* __restrict__ gsq,
                           _Float16* __restrict__ qh, _Float16* __restrict__ ql,
                           float* __restrict__ qsq) {
    __shared__ float red[4];
    int tid = threadIdx.x;
    const float* src; _Float16* dh; _Float16* dl; float* nrm;
    if (blockIdx.x < NCODES) {
        size_t n = blockIdx.x;
        src = ctx + n * QD; dh = gh + n * QD; dl = gl + n * QD; nrm = gsq + n;
    } else {
        size_t b = blockIdx.x - NCODES;
        src = q + b * QD; dh = qh + b * QD; dl = ql + b * QD; nrm = qsq + b;
    }
    int c = tid * 8;
    float4 t0 = *(const float4*)(src + c);
    float4 t1 = *(const float4*)(src + c + 4);
    float s = t0.x * t0.x + t0.y * t0.y + t0.z * t0.z + t0.w * t0.w
            + t1.x * t1.x + t1.y * t1.y + t1.z * t1.z + t1.w * t1.w;
    f16x8 h, l;
    h[0] = (_Float16)t0.x; l[0] = (_Float16)(t0.x - (float)h[0]);
    h[1] = (_Float16)t0.y; l[1] = (_Float16)(t0.y - (float)h[1]);
    h[2] = (_Float16)t0.z; l[2] = (_Float16)(t0.z - (float)h[2]);
    h[3] = (_Float16)t0.w; l[3] = (_Float16)(t0.w - (float)h[3]);
    h[4] = (_Float16)t1.x; l[4] = (_Float16)(t1.x - (float)h[4]);
    h[5] = (_Float16)t1.y; l[5] = (_Float16)(t1.y - (float)h[5]);
    h[6] = (_Float16)t1.z; l[6] = (_Float16)(t1.z - (float)h[6]);
    h[7] = (_Float16)t1.w; l[7] = (_Float16)(t1.w - (float)h[7]);
    *(f16x8*)(dh + c) = h;
    *(f16x8*)(dl + c) = l;
    for (int off = 32; off > 0; off >>= 1) s += __shfl_down(s, off);
    if ((tid & 63) == 0) red[tid >> 6] = s;
    __syncthreads();
    if (tid == 0) *nrm = red[0] + red[1] + red[2] + red[3];
}

// ---------------- K1b: r13 fallback prep (ctx split + gsq, qsq) -- used when
// d_ws is too small for the q pre-split path.
__global__ void k_prep_r13(const float* __restrict__ ctx, const float* __restrict__ q,
                           _Float16* __restrict__ gh, _Float16* __restrict__ gl,
                           float* __restrict__ gsq, float* __restrict__ qsq) {
    int tid = threadIdx.x;
    if (blockIdx.x < NCODES) {
        __shared__ float red[4];
        int n = blockIdx.x;
        float s = 0.f;
#pragma unroll
        for (int i = 0; i < 2; ++i) {
            int c = (tid + i * 256) * 4;
            float4 t = *(const float4*)(ctx + (size_t)n * QD + c);
            f16x4 h, l;
            h[0] = (_Float16)t.x; l[0] = (_Float16)(t.x - (float)h[0]);
            h[1] = (_Float16)t.y; l[1] = (_Float16)(t.y - (float)h[1]);
            h[2] = (_Float16)t.z; l[2] = (_Float16)(t.z - (float)h[2]);
            h[3] = (_Float16)t.w; l[3] = (_Float16)(t.w - (float)h[3]);
            *(f16x4*)(gh + (size_t)n * QD + c) = h;
            *(f16x4*)(gl + (size_t)n * QD + c) = l;
            s += t.x * t.x + t.y * t.y + t.z * t.z + t.w * t.w;
        }
        for (int off = 32; off > 0; off >>= 1) s += __shfl_down(s, off);
        if ((tid & 63) == 0) red[tid >> 6] = s;
        __syncthreads();
        if (tid == 0) gsq[n] = red[0] + red[1] + red[2] + red[3];
    } else {
        int w = tid >> 6, lane = tid & 63;
        int b = (blockIdx.x - NCODES) * 4 + w;
        const float4* row = (const float4*)(q + (size_t)b * QD);
        float s = 0.f;
#pragma unroll
        for (int i = 0; i < 8; ++i) {
            float4 v = row[lane + i * 64];
            s += v.x * v.x + v.y * v.y + v.z * v.z + v.w * v.w;
        }
        for (int off = 32; off > 0; off >>= 1) s += __shfl_down(s, off);
        if (lane == 0) qsq[b] = s;
    }
}

// ---------------- K2a: distance GEMM, BOTH operands pre-split + global_load_lds ----
// r5/r13 structure (2-barrier, 227us) with stage A replaced by a mirror of the
// PROVEN stage-B async path: identical 128x64 tile geometry, identical linear LDS
// dest + inverse-swizzled per-lane source, identical fragment reads. Deletes the
// in-loop q->fp16 convert (was 33% VALUBusy). Sync structure untouched.
__launch_bounds__(256)
__global__ void k_dist_pre(const _Float16* __restrict__ qh, const _Float16* __restrict__ ql,
                           const _Float16* __restrict__ gh, const _Float16* __restrict__ gl,
                           const float* __restrict__ gsq,
                           float* __restrict__ pval, int* __restrict__ pidx) {
    __shared__ _Float16 ah[128][64];
    __shared__ _Float16 al[128][64];
    __shared__ _Float16 bh[128][64];
    __shared__ _Float16 bl[128][64];

    const int tid = threadIdx.x;
    const int lane = tid & 63, wid = tid >> 6;
    const int wr = wid >> 1, wc = wid & 1;
    const int n0 = blockIdx.x;
    const int xcd = n0 & 7, j = n0 >> 3;
    const int col = j & 7, rowt = xcd * 16 + (j >> 3);
    const int colBase = col * 128, rowBase = rowt * 128;
    const int fr = lane & 15, kg = lane >> 4;

    char* ahB = (char*)&ah[0][0];
    char* alB = (char*)&al[0][0];
    const char* bhB = (const char*)&bh[0][0];
    const char* blB = (const char*)&bl[0][0];

    // shared staging geometry (r5-proven): 8-row group, pre-XORed 16B granule
    const int srow = lane >> 3;
    const int gran = (lane & 7) ^ (lane >> 3);

    f32x4 acc[4][4];
#pragma unroll
    for (int m = 0; m < 4; ++m)
#pragma unroll
        for (int n = 0; n < 4; ++n) acc[m][n] = (f32x4)0.f;

    for (int kb = 0; kb < QD; kb += 64) {
        __syncthreads();
        // stage A: async from qh/ql (mirror of stage B)
#pragma unroll
        for (int i = 0; i < 4; ++i) {
            int g = wid * 4 + i;
            size_t aoff = (size_t)(rowBase + g * 8 + srow) * QD + kb + gran * 8;
            async_copy16(qh + aoff, &ah[g * 8][0]);
            async_copy16(ql + aoff, &al[g * 8][0]);
        }
        // stage B: async from gh/gl (unchanged)
#pragma unroll
        for (int i = 0; i < 4; ++i) {
            int g = wid * 4 + i;
            size_t goff = (size_t)(colBase + g * 8 + srow) * QD + kb + gran * 8;
            async_copy16(gh + goff, &bh[g * 8][0]);
            async_copy16(gl + goff, &bl[g * 8][0]);
        }
        __syncthreads();  // drains vmcnt (gload_lds)

#pragma unroll
        for (int h = 0; h < 2; ++h) {
            f16x8 a_h[4], a_l[4], b_h[4], b_l[4];
#pragma unroll
            for (int m = 0; m < 4; ++m) {
                int ar = wr * 64 + m * 16 + fr;
                int off = ar * 128 + ((h * 64 + kg * 16) ^ ((ar & 7) << 4));
                a_h[m] = *(const f16x8*)(ahB + off);
                a_l[m] = *(const f16x8*)(alB + off);
            }
#pragma unroll
            for (int n = 0; n < 4; ++n) {
                int br = wc * 64 + n * 16 + fr;
                int off = br * 128 + ((h * 64 + kg * 16) ^ ((br & 7) << 4));
                b_h[n] = *(const f16x8*)(bhB + off);
                b_l[n] = *(const f16x8*)(blB + off);
            }
#pragma unroll
            for (int m = 0; m < 4; ++m)
#pragma unroll
                for (int n = 0; n < 4; ++n) {
                    acc[m][n] = __builtin_amdgcn_mfma_f32_16x16x32_f16(a_h[m], b_h[n], acc[m][n], 0, 0, 0);
                    acc[m][n] = __builtin_amdgcn_mfma_f32_16x16x32_f16(a_h[m], b_l[n], acc[m][n], 0, 0, 0);
                    acc[m][n] = __builtin_amdgcn_mfma_f32_16x16x32_f16(a_l[m], b_h[n], acc[m][n], 0, 0, 0);
                }
        }
    }

    // epilogue: d = gsq - 2*dot; per-row argmin (first-occurrence ties)
    float mv[4][4]; int mi[4][4];
#pragma unroll
    for (int m = 0; m < 4; ++m)
#pragma unroll
        for (int r = 0; r < 4; ++r) { mv[m][r] = FLT_MAX; mi[m][r] = 0x7fffffff; }
#pragma unroll
    for (int n = 0; n < 4; ++n) {
        int c = colBase + wc * 64 + n * 16 + fr;
        float gq = gsq[c];
#pragma unroll
        for (int m = 0; m < 4; ++m)
#pragma unroll
            for (int r = 0; r < 4; ++r) {
                float d = gq - 2.0f * acc[m][n][r];
                if (d < mv[m][r]) { mv[m][r] = d; mi[m][r] = c; }
            }
    }
#pragma unroll
    for (int off = 1; off < 16; off <<= 1) {
#pragma unroll
        for (int m = 0; m < 4; ++m)
#pragma unroll
            for (int r = 0; r < 4; ++r) {
                float ov = __shfl_xor(mv[m][r], off);
                int   oi = __shfl_xor(mi[m][r], off);
                if (ov < mv[m][r] || (ov == mv[m][r] && oi < mi[m][r])) { mv[m][r] = ov; mi[m][r] = oi; }
            }
    }
    if (fr == 0) {
        const size_t slot = (size_t)(col * 2 + wc) * BSZ;
#pragma unroll
        for (int m = 0; m < 4; ++m)
#pragma unroll
            for (int r = 0; r < 4; ++r) {
                int grow = rowBase + wr * 64 + m * 16 + kg * 4 + r;
                pval[slot + grow] = mv[m][r];
                pidx[slot + grow] = mi[m][r];
            }
    }
}

// ---------------- K2b: r13 fallback distance GEMM (in-loop q split) -- 227us ----
__launch_bounds__(256)
__global__ void k_dist_r13(const float* __restrict__ q, const _Float16* __restrict__ gh,
                           const _Float16* __restrict__ gl, const float* __restrict__ gsq,
                           float* __restrict__ pval, int* __restrict__ pidx) {
    __shared__ _Float16 ah[128][64];
    __shared__ _Float16 al[128][64];
    __shared__ _Float16 bh[128][64];
    __shared__ _Float16 bl[128][64];

    const int tid = threadIdx.x;
    const int lane = tid & 63, wid = tid >> 6;
    const int wr = wid >> 1, wc = wid & 1;
    const int n0 = blockIdx.x;
    const int xcd = n0 & 7, j = n0 >> 3;
    const int col = j & 7, rowt = xcd * 16 + (j >> 3);
    const int colBase = col * 128, rowBase = rowt * 128;
    const int fr = lane & 15, kg = lane >> 4;

    char* ahB = (char*)&ah[0][0];
    char* alB = (char*)&al[0][0];
    const char* bhB = (const char*)&bh[0][0];
    const char* blB = (const char*)&bl[0][0];

    f32x4 acc[4][4];
#pragma unroll
    for (int m = 0; m < 4; ++m)
#pragma unroll
        for (int n = 0; n < 4; ++n) acc[m][n] = (f32x4)0.f;

    for (int kb = 0; kb < QD; kb += 64) {
        __syncthreads();
#pragma unroll
        for (int s = 0; s < 8; ++s) {
            int f = s * 256 + tid;
            int row = f >> 4, k4 = (f & 15) * 4;
            float4 t = *(const float4*)(q + (size_t)(rowBase + row) * QD + kb + k4);
            f16x4 h, l;
            h[0] = (_Float16)t.x; l[0] = (_Float16)(t.x - (float)h[0]);
            h[1] = (_Float16)t.y; l[1] = (_Float16)(t.y - (float)h[1]);
            h[2] = (_Float16)t.z; l[2] = (_Float16)(t.z - (float)h[2]);
            h[3] = (_Float16)t.w; l[3] = (_Float16)(t.w - (float)h[3]);
            int byt = (row * 128 + k4 * 2) ^ ((row & 7) << 4);
            *(f16x4*)(ahB + byt) = h;
            *(f16x4*)(alB + byt) = l;
        }
#pragma unroll
        for (int i = 0; i < 4; ++i) {
            int g = wid * 4 + i;
            int row = g * 8 + (lane >> 3);
            int gran = (lane & 7) ^ (lane >> 3);
            size_t goff = (size_t)(colBase + row) * QD + kb + gran * 8;
            async_copy16(gh + goff, &bh[g * 8][0]);
            async_copy16(gl + goff, &bl[g * 8][0]);
        }
        __syncthreads();

#pragma unroll
        for (int h = 0; h < 2; ++h) {
            f16x8 a_h[4], a_l[4], b_h[4], b_l[4];
#pragma unroll
            for (int m = 0; m < 4; ++m) {
                int ar = wr * 64 + m * 16 + fr;
                int off = ar * 128 + ((h * 64 + kg * 16) ^ ((ar & 7) << 4));
                a_h[m] = *(const f16x8*)(ahB + off);
                a_l[m] = *(const f16x8*)(alB + off);
            }
#pragma unroll
            for (int n = 0; n < 4; ++n) {
                int br = wc * 64 + n * 16 + fr;
                int off = br * 128 + ((h * 64 + kg * 16) ^ ((br & 7) << 4));
                b_h[n] = *(const f16x8*)(bhB + off);
                b_l[n] = *(const f16x8*)(blB + off);
            }
#pragma unroll
            for (int m = 0; m < 4; ++m)
#pragma unroll
                for (int n = 0; n < 4; ++n) {
                    acc[m][n] = __builtin_amdgcn_mfma_f32_16x16x32_f16(a_h[m], b_h[n], acc[m][n], 0, 0, 0);
                    acc[m][n] = __builtin_amdgcn_mfma_f32_16x16x32_f16(a_h[m], b_l[n], acc[m][n], 0, 0, 0);
                    acc[m][n] = __builtin_amdgcn_mfma_f32_16x16x32_f16(a_l[m], b_h[n], acc[m][n], 0, 0, 0);
                }
        }
    }

    float mv[4][4]; int mi[4][4];
#pragma unroll
    for (int m = 0; m < 4; ++m)
#pragma unroll
        for (int r = 0; r < 4; ++r) { mv[m][r] = FLT_MAX; mi[m][r] = 0x7fffffff; }
#pragma unroll
    for (int n = 0; n < 4; ++n) {
        int c = colBase + wc * 64 + n * 16 + fr;
        float gq = gsq[c];
#pragma unroll
        for (int m = 0; m < 4; ++m)
#pragma unroll
            for (int r = 0; r < 4; ++r) {
                float d = gq - 2.0f * acc[m][n][r];
                if (d < mv[m][r]) { mv[m][r] = d; mi[m][r] = c; }
            }
    }
#pragma unroll
    for (int off = 1; off < 16; off <<= 1) {
#pragma unroll
        for (int m = 0; m < 4; ++m)
#pragma unroll
            for (int r = 0; r < 4; ++r) {
                float ov = __shfl_xor(mv[m][r], off);
                int   oi = __shfl_xor(mi[m][r], off);
                if (ov < mv[m][r] || (ov == mv[m][r] && oi < mi[m][r])) { mv[m][r] = ov; mi[m][r] = oi; }
            }
    }
    if (fr == 0) {
        const size_t slot = (size_t)(col * 2 + wc) * BSZ;
#pragma unroll
        for (int m = 0; m < 4; ++m)
#pragma unroll
            for (int r = 0; r < 4; ++r) {
                int grow = rowBase + wr * 64 + m * 16 + kg * 4 + r;
                pval[slot + grow] = mv[m][r];
                pidx[slot + grow] = mi[m][r];
            }
    }
}

// ---------------- K3: merge 16 partials -> argmin + fused qld + fused chunk-hist ----
__global__ void k_merge(const float* __restrict__ pval, const int* __restrict__ pidx,
                        const float* __restrict__ qsq,
                        int* __restrict__ idx_out, float* __restrict__ qld,
                        int* __restrict__ chunkhist) {
    __shared__ int h[NCODES];
    int c = blockIdx.x, tid = threadIdx.x;
    int b = c * 256 + tid;
#pragma unroll
    for (int s = 0; s < 4; ++s) h[tid + s * 256] = 0;
    float bv = pval[b]; int bi = pidx[b];
    for (int y = 1; y < NCOLG; ++y) {
        float v = pval[(size_t)y * BSZ + b]; int ii = pidx[(size_t)y * BSZ + b];
        if (v < bv || (v == bv && ii < bi)) { bv = v; bi = ii; }
    }
    idx_out[b] = bi;
    qld[b] = (qsq[b] + bv) * (1.0f / (float)QD);
    __syncthreads();
    atomicAdd(&h[bi], 1);
    __syncthreads();
#pragma unroll
    for (int s = 0; s < 4; ++s) chunkhist[c * NCODES + tid + s * 256] = h[tid + s * 256];
}

// ---------------- K4: scan (counting sort) + fused ec ----------------
__global__ void k_scan(const int* __restrict__ chunkhist, int* __restrict__ base,
                       int* __restrict__ counts, int* __restrict__ offsets,
                       const float* __restrict__ ema_count, float* __restrict__ ec_out) {
    __shared__ int s[NCODES];
    __shared__ float e2[NCODES];
    int code = threadIdx.x;  // 1024 threads
    int run = 0;
    for (int c = 0; c < NCHUNK; ++c) {
        base[c * NCODES + code] = run;
        run += chunkhist[c * NCODES + code];
    }
    counts[code] = run;
    s[code] = run; __syncthreads();
    for (int off = 1; off < NCODES; off <<= 1) {
        int v = (code >= off) ? s[code - off] : 0;
        __syncthreads();
        s[code] += v; __syncthreads();
    }
    offsets[code] = s[code] - run;
    float er = 0.99f * ema_count[code] + one_minus_decay() * (float)run;
    e2[code] = er; __syncthreads();
    for (int off = 512; off > 0; off >>= 1) {
        if (code < off) e2[code] += e2[code + off];
        __syncthreads();
    }
    float n = e2[0];
    ec_out[code] = (er + 1e-5f) / (n + (float)(2048.0 * 1e-5)) * n;
}

__global__ void k_fill(const int* __restrict__ idx, const int* __restrict__ base,
                       const int* __restrict__ offsets, int* __restrict__ list) {
    __shared__ int sidx[256];
    int c = blockIdx.x, tid = threadIdx.x;
    int b = c * 256 + tid;
    int n = idx[b];
    sidx[tid] = n; __syncthreads();
    int rank = 0;
    for (int j = 0; j < tid; ++j) rank += (sidx[j] == n);
    list[offsets[n] + base[c * NCODES + n] + rank] = b;
}

// ---------------- K6: q_hat segment-sum, parallel over (code, col-group) ----------------
__global__ void k_qhat(const float* __restrict__ q, const int* __restrict__ counts,
                       const int* __restrict__ offsets, const int* __restrict__ list,
                       float* __restrict__ qhat) {
    int n = blockIdx.x;
    int col = blockIdx.y * 256 + threadIdx.x;
    int cnt = counts[n];
    const int* lp = list + offsets[n];
    float a0 = 0.f, a1 = 0.f, a2 = 0.f, a3 = 0.f, a4 = 0.f, a5 = 0.f, a6 = 0.f, a7 = 0.f;
    int i = 0;
    for (; i + 8 <= cnt; i += 8) {
        int b0 = lp[i], b1 = lp[i + 1], b2 = lp[i + 2], b3 = lp[i + 3];
        int b4 = lp[i + 4], b5 = lp[i + 5], b6 = lp[i + 6], b7 = lp[i + 7];
        a0 += q[(size_t)b0 * QD + col]; a1 += q[(size_t)b1 * QD + col];
        a2 += q[(size_t)b2 * QD + col]; a3 += q[(size_t)b3 * QD + col];
        a4 += q[(size_t)b4 * QD + col]; a5 += q[(size_t)b5 * QD + col];
        a6 += q[(size_t)b6 * QD + col]; a7 += q[(size_t)b7 * QD + col];
    }
    for (; i < cnt; ++i) a0 += q[(size_t)lp[i] * QD + col];
    float r = ((a0 + a1) + (a2 + a3)) + ((a4 + a5) + (a6 + a7));
    qhat[(size_t)n * QD + col] = r;
}

// ---------------- K8: finalize edw / context_new / out_context ----------------
__global__ void k_fin(const float* __restrict__ ema_dw, const float* __restrict__ ec,
                      const float* qhat, float* edw_out, float* ctxnew_out,
                      float* outctx_out) {
    size_t i = ((size_t)blockIdx.x * 256 + threadIdx.x) * 8;
    int n = (int)(i >> 11);
    float e = ec[n];
    float om = one_minus_decay();
#pragma unroll
    for (int h = 0; h < 2; ++h) {
        float4 dw = *(const float4*)(ema_dw + i + h * 4);
        float4 qh = *(const float4*)(qhat + i + h * 4);
        float4 ed, cn;
        ed.x = 0.99f * dw.x + om * qh.x; ed.y = 0.99f * dw.y + om * qh.y;
        ed.z = 0.99f * dw.z + om * qh.z; ed.w = 0.99f * dw.w + om * qh.w;
        cn.x = ed.x / e; cn.y = ed.y / e; cn.z = ed.z / e; cn.w = ed.w / e;
        *(float4*)(edw_out + i + h * 4) = ed;
        *(float4*)(ctxnew_out + i + h * 4) = cn;
        *(float4*)(outctx_out + i + h * 4) = cn;
    }
}

extern "C" void kernel_launch(void* const* d_in, const int* in_sizes, int n_in,
                              void* d_out, int out_size, void* d_ws, size_t ws_size,
                              hipStream_t stream) {
    const float* q         = (const float*)d_in[0];
    const float* ctx       = (const float*)d_in[1];
    const float* ema_count = (const float*)d_in[2];
    const float* ema_dw    = (const float*)d_in[3];

    float* out = (float*)d_out;
    float* o_qld    = out;                              // 16384
    float* o_outctx = out + BSZ;                        // 2097152
    float* o_ec     = o_outctx + (size_t)NCODES * QD;   // 1024
    float* o_edw    = o_ec + NCODES;                    // 2097152
    float* o_ctxnew = o_edw + (size_t)NCODES * QD;      // 2097152

    char* w = (char*)d_ws;
    float* ws_gsq   = (float*)w;                        // 1024 f
    int* ws_idx     = (int*)(w + 4096);                 // 16384 i
    int* ws_counts  = (int*)(w + 4096 + 65536);         // 1024 i
    int* ws_offsets = ws_counts + NCODES;               // 1024 i
    int* ws_list    = ws_offsets + NCODES;              // 16384 i

    // q pre-split scratch (128 MB) at ws + 1MB, if available
    const size_t presplit_need = (size_t)1048576 + (size_t)2 * BSZ * QD * sizeof(_Float16);
    const bool use_pre = (ws_size >= presplit_need);
    _Float16* qh = (_Float16*)(w + 1048576);
    _Float16* ql = qh + (size_t)BSZ * QD;

    // scratch carved from not-yet-written d_out regions:
    _Float16* gh = (_Float16*)o_ctxnew;                 // 4MB (dead after k_dist)
    _Float16* gl = gh + (size_t)NCODES * QD;            // 4MB
    float* pval  = o_edw;                               // 1MB (dead after k_merge)
    int*   pidx  = (int*)(o_edw + (size_t)NCOLG * BSZ); // 1MB
    float* qsq   = o_edw + (size_t)2 * NCOLG * BSZ;     // 64KB (dead after k_merge)
    int* chunkhist = (int*)o_outctx;                    // 256KB (dead after k_scan)
    int* basep     = chunkhist + NCHUNK * NCODES;       // 256KB (dead after k_fill)
    float* qhat    = o_outctx;                          // 8MB (finalized by k_fin)

    if (use_pre) {
        k_prep_all<<<NCODES + BSZ, 256, 0, stream>>>(ctx, q, gh, gl, ws_gsq, qh, ql, qsq);
        k_dist_pre<<<1024, 256, 0, stream>>>(qh, ql, gh, gl, ws_gsq, pval, pidx);
    } else {
        k_prep_r13<<<NCODES + BSZ / 4, 256, 0, stream>>>(ctx, q, gh, gl, ws_gsq, qsq);
        k_dist_r13<<<1024, 256, 0, stream>>>(q, gh, gl, ws_gsq, pval, pidx);
    }
    k_merge <<<NCHUNK, 256, 0, stream>>>(pval, pidx, qsq, ws_idx, o_qld, chunkhist);
    k_scan  <<<1, 1024, 0, stream>>>(chunkhist, basep, ws_counts, ws_offsets, ema_count, o_ec);
    k_fill  <<<NCHUNK, 256, 0, stream>>>(ws_idx, basep, ws_offsets, ws_list);
    k_qhat  <<<dim3(NCODES, 8), 256, 0, stream>>>(q, ws_counts, ws_offsets, ws_list, qhat);
    k_fin   <<<NCODES * QD / 2048, 256, 0, stream>>>(ema_dw, o_ec, qhat,
                                                     o_edw, o_ctxnew, o_outctx);
}

// Round 16
// 262.989 us; speedup vs baseline: 1.2804x; 1.2804x over previous
//
#include <hip/hip_runtime.h>
#include <hip/hip_bf16.h>
#include <float.h>

#define BSZ 16384
#define NCODES 1024
#define QD 2048
#define NCHUNK 64   // BSZ / 256
#define NCOLG 16    // 8 col-blocks x 2 wc-waves

typedef _Float16 f16x8 __attribute__((ext_vector_type(8)));
typedef _Float16 f16x4 __attribute__((ext_vector_type(4)));
typedef float f32x4 __attribute__((ext_vector_type(4)));

static __device__ __forceinline__ float one_minus_decay() { return (float)(1.0 - 0.99); }

static __device__ __forceinline__ void async_copy16(const void* src, void* lds) {
    __builtin_amdgcn_global_load_lds((const __attribute__((address_space(1))) void*)src,
                                     (__attribute__((address_space(3))) void*)lds, 16, 0, 0);
}

// ---------------- K1: fused prep -- ctx split hi/lo + gsq (blocks 0..1023), qsq ----
__global__ void k_prep(const float* __restrict__ ctx, const float* __restrict__ q,
                       _Float16* __restrict__ gh, _Float16* __restrict__ gl,
                       float* __restrict__ gsq, float* __restrict__ qsq) {
    int tid = threadIdx.x;
    if (blockIdx.x < NCODES) {
        __shared__ float red[4];
        int n = blockIdx.x;
        float s = 0.f;
#pragma unroll
        for (int i = 0; i < 2; ++i) {
            int c = (tid + i * 256) * 4;
            float4 t = *(const float4*)(ctx + (size_t)n * QD + c);
            f16x4 h, l;
            h[0] = (_Float16)t.x; l[0] = (_Float16)(t.x - (float)h[0]);
            h[1] = (_Float16)t.y; l[1] = (_Float16)(t.y - (float)h[1]);
            h[2] = (_Float16)t.z; l[2] = (_Float16)(t.z - (float)h[2]);
            h[3] = (_Float16)t.w; l[3] = (_Float16)(t.w - (float)h[3]);
            *(f16x4*)(gh + (size_t)n * QD + c) = h;
            *(f16x4*)(gl + (size_t)n * QD + c) = l;
            s += t.x * t.x + t.y * t.y + t.z * t.z + t.w * t.w;
        }
        for (int off = 32; off > 0; off >>= 1) s += __shfl_down(s, off);
        if ((tid & 63) == 0) red[tid >> 6] = s;
        __syncthreads();
        if (tid == 0) gsq[n] = red[0] + red[1] + red[2] + red[3];
    } else {
        int w = tid >> 6, lane = tid & 63;
        int b = (blockIdx.x - NCODES) * 4 + w;
        const float4* row = (const float4*)(q + (size_t)b * QD);
        float s = 0.f;
#pragma unroll
        for (int i = 0; i < 8; ++i) {
            float4 v = row[lane + i * 64];
            s += v.x * v.x + v.y * v.y + v.z * v.z + v.w * v.w;
        }
        for (int off = 32; off > 0; off >>= 1) s += __shfl_down(s, off);
        if (lane == 0) qsq[b] = s;
    }
}

// ---------------- K2: 2-TERM split-fp16 MFMA distance GEMM + per-tile argmin --------
// r13's proven 227us structure with the A-side lo term DELETED:
//   dot ~= qh.gh + qh.gl = qh.(gh+gl) ~= qh.g ; error = (q-qh).g, sigma(d) ~ 0.013.
// Expected index flips ~10-20 of 16384 (typical 1st-2nd gap ~45) -> absmax ~0.03,
// under the 0.196 threshold. Gains: 48->32 MFMA/K-iter, stage-A cvt work halved,
// a_l fragment reads gone, LDS 64->48KB. Everything else byte-identical to r13.
// (Ledger: do NOT re-try BK=32 / dbuf-1barrier / 32x32 MFMA / qsq-fusion /
//  stage-B-first / 512-thr -- all measured regressions.)
__launch_bounds__(256)
__global__ void k_dist(const float* __restrict__ q, const _Float16* __restrict__ gh,
                       const _Float16* __restrict__ gl, const float* __restrict__ gsq,
                       float* __restrict__ pval, int* __restrict__ pidx) {
    __shared__ _Float16 ah[128][64];
    __shared__ _Float16 bh[128][64];
    __shared__ _Float16 bl[128][64];

    const int tid = threadIdx.x;
    const int lane = tid & 63, wid = tid >> 6;
    const int wr = wid >> 1, wc = wid & 1;
    // XCD-chunked mapping: 8 col-blocks of one row-tile dispatch-adjacent on one XCD.
    const int n0 = blockIdx.x;
    const int xcd = n0 & 7, j = n0 >> 3;
    const int col = j & 7, rowt = xcd * 16 + (j >> 3);
    const int colBase = col * 128, rowBase = rowt * 128;
    const int fr = lane & 15, kg = lane >> 4;

    char* ahB = (char*)&ah[0][0];
    const char* bhB = (const char*)&bh[0][0];
    const char* blB = (const char*)&bl[0][0];

    f32x4 acc[4][4];
#pragma unroll
    for (int m = 0; m < 4; ++m)
#pragma unroll
        for (int n = 0; n < 4; ++n) acc[m][n] = (f32x4)0.f;

    for (int kb = 0; kb < QD; kb += 64) {
        __syncthreads();
        // stage A: q fp32 -> fp16 (hi only), swizzled ds_write
#pragma unroll
        for (int s = 0; s < 8; ++s) {
            int f = s * 256 + tid;
            int row = f >> 4, k4 = (f & 15) * 4;
            float4 t = *(const float4*)(q + (size_t)(rowBase + row) * QD + kb + k4);
            f16x4 h;
            h[0] = (_Float16)t.x; h[1] = (_Float16)t.y;
            h[2] = (_Float16)t.z; h[3] = (_Float16)t.w;
            int byt = (row * 128 + k4 * 2) ^ ((row & 7) << 4);
            *(f16x4*)(ahB + byt) = h;
        }
        // stage B: linear LDS dest, inverse-swizzled per-lane global source
#pragma unroll
        for (int i = 0; i < 4; ++i) {
            int g = wid * 4 + i;                 // 8-row group, 0..15
            int row = g * 8 + (lane >> 3);
            int gran = (lane & 7) ^ (lane >> 3); // 16B granule, pre-XORed
            size_t goff = (size_t)(colBase + row) * QD + kb + gran * 8;
            async_copy16(gh + goff, &bh[g * 8][0]);
            async_copy16(gl + goff, &bl[g * 8][0]);
        }
        __syncthreads();  // drains vmcnt (gload_lds) + lgkmcnt

#pragma unroll
        for (int h = 0; h < 2; ++h) {
            f16x8 a_h[4], b_h[4], b_l[4];
#pragma unroll
            for (int m = 0; m < 4; ++m) {
                int ar = wr * 64 + m * 16 + fr;
                int off = ar * 128 + ((h * 64 + kg * 16) ^ ((ar & 7) << 4));
                a_h[m] = *(const f16x8*)(ahB + off);
            }
#pragma unroll
            for (int n = 0; n < 4; ++n) {
                int br = wc * 64 + n * 16 + fr;
                int off = br * 128 + ((h * 64 + kg * 16) ^ ((br & 7) << 4));
                b_h[n] = *(const f16x8*)(bhB + off);
                b_l[n] = *(const f16x8*)(blB + off);
            }
#pragma unroll
            for (int m = 0; m < 4; ++m)
#pragma unroll
                for (int n = 0; n < 4; ++n) {
                    acc[m][n] = __builtin_amdgcn_mfma_f32_16x16x32_f16(a_h[m], b_h[n], acc[m][n], 0, 0, 0);
                    acc[m][n] = __builtin_amdgcn_mfma_f32_16x16x32_f16(a_h[m], b_l[n], acc[m][n], 0, 0, 0);
                }
        }
    }

    // epilogue: d = gsq - 2*dot; per-row argmin (first-occurrence ties)
    float mv[4][4]; int mi[4][4];
#pragma unroll
    for (int m = 0; m < 4; ++m)
#pragma unroll
        for (int r = 0; r < 4; ++r) { mv[m][r] = FLT_MAX; mi[m][r] = 0x7fffffff; }
#pragma unroll
    for (int n = 0; n < 4; ++n) {
        int c = colBase + wc * 64 + n * 16 + fr;
        float gq = gsq[c];
#pragma unroll
        for (int m = 0; m < 4; ++m)
#pragma unroll
            for (int r = 0; r < 4; ++r) {
                float d = gq - 2.0f * acc[m][n][r];
                if (d < mv[m][r]) { mv[m][r] = d; mi[m][r] = c; }
            }
    }
#pragma unroll
    for (int off = 1; off < 16; off <<= 1) {
#pragma unroll
        for (int m = 0; m < 4; ++m)
#pragma unroll
            for (int r = 0; r < 4; ++r) {
                float ov = __shfl_xor(mv[m][r], off);
                int   oi = __shfl_xor(mi[m][r], off);
                if (ov < mv[m][r] || (ov == mv[m][r] && oi < mi[m][r])) { mv[m][r] = ov; mi[m][r] = oi; }
            }
    }
    if (fr == 0) {
        const size_t slot = (size_t)(col * 2 + wc) * BSZ;
#pragma unroll
        for (int m = 0; m < 4; ++m)
#pragma unroll
            for (int r = 0; r < 4; ++r) {
                int grow = rowBase + wr * 64 + m * 16 + kg * 4 + r;
                pval[slot + grow] = mv[m][r];
                pidx[slot + grow] = mi[m][r];
            }
    }
}

// ---------------- K3: merge 16 partials -> argmin + fused qld + fused chunk-hist ----
__global__ void k_merge(const float* __restrict__ pval, const int* __restrict__ pidx,
                        const float* __restrict__ qsq,
                        int* __restrict__ idx_out, float* __restrict__ qld,
                        int* __restrict__ chunkhist) {
    __shared__ int h[NCODES];
    int c = blockIdx.x, tid = threadIdx.x;
    int b = c * 256 + tid;
#pragma unroll
    for (int s = 0; s < 4; ++s) h[tid + s * 256] = 0;
    float bv = pval[b]; int bi = pidx[b];
    for (int y = 1; y < NCOLG; ++y) {
        float v = pval[(size_t)y * BSZ + b]; int ii = pidx[(size_t)y * BSZ + b];
        if (v < bv || (v == bv && ii < bi)) { bv = v; bi = ii; }
    }
    idx_out[b] = bi;
    qld[b] = (qsq[b] + bv) * (1.0f / (float)QD);
    __syncthreads();
    atomicAdd(&h[bi], 1);
    __syncthreads();
#pragma unroll
    for (int s = 0; s < 4; ++s) chunkhist[c * NCODES + tid + s * 256] = h[tid + s * 256];
}

// ---------------- K4: scan (counting sort) + fused ec ----------------
__global__ void k_scan(const int* __restrict__ chunkhist, int* __restrict__ base,
                       int* __restrict__ counts, int* __restrict__ offsets,
                       const float* __restrict__ ema_count, float* __restrict__ ec_out) {
    __shared__ int s[NCODES];
    __shared__ float e2[NCODES];
    int code = threadIdx.x;  // 1024 threads
    int run = 0;
    for (int c = 0; c < NCHUNK; ++c) {
        base[c * NCODES + code] = run;
        run += chunkhist[c * NCODES + code];
    }
    counts[code] = run;
    s[code] = run; __syncthreads();
    for (int off = 1; off < NCODES; off <<= 1) {
        int v = (code >= off) ? s[code - off] : 0;
        __syncthreads();
        s[code] += v; __syncthreads();
    }
    offsets[code] = s[code] - run;
    float er = 0.99f * ema_count[code] + one_minus_decay() * (float)run;
    e2[code] = er; __syncthreads();
    for (int off = 512; off > 0; off >>= 1) {
        if (code < off) e2[code] += e2[code + off];
        __syncthreads();
    }
    float n = e2[0];
    ec_out[code] = (er + 1e-5f) / (n + (float)(2048.0 * 1e-5)) * n;
}

__global__ void k_fill(const int* __restrict__ idx, const int* __restrict__ base,
                       const int* __restrict__ offsets, int* __restrict__ list) {
    __shared__ int sidx[256];
    int c = blockIdx.x, tid = threadIdx.x;
    int b = c * 256 + tid;
    int n = idx[b];
    sidx[tid] = n; __syncthreads();
    int rank = 0;
    for (int j = 0; j < tid; ++j) rank += (sidx[j] == n);
    list[offsets[n] + base[c * NCODES + n] + rank] = b;
}

// ---------------- K6: q_hat segment-sum, parallel over (code, col-group) ----------------
__global__ void k_qhat(const float* __restrict__ q, const int* __restrict__ counts,
                       const int* __restrict__ offsets, const int* __restrict__ list,
                       float* __restrict__ qhat) {
    int n = blockIdx.x;
    int col = blockIdx.y * 256 + threadIdx.x;
    int cnt = counts[n];
    const int* lp = list + offsets[n];
    float a0 = 0.f, a1 = 0.f, a2 = 0.f, a3 = 0.f, a4 = 0.f, a5 = 0.f, a6 = 0.f, a7 = 0.f;
    int i = 0;
    for (; i + 8 <= cnt; i += 8) {
        int b0 = lp[i], b1 = lp[i + 1], b2 = lp[i + 2], b3 = lp[i + 3];
        int b4 = lp[i + 4], b5 = lp[i + 5], b6 = lp[i + 6], b7 = lp[i + 7];
        a0 += q[(size_t)b0 * QD + col]; a1 += q[(size_t)b1 * QD + col];
        a2 += q[(size_t)b2 * QD + col]; a3 += q[(size_t)b3 * QD + col];
        a4 += q[(size_t)b4 * QD + col]; a5 += q[(size_t)b5 * QD + col];
        a6 += q[(size_t)b6 * QD + col]; a7 += q[(size_t)b7 * QD + col];
    }
    for (; i < cnt; ++i) a0 += q[(size_t)lp[i] * QD + col];
    float r = ((a0 + a1) + (a2 + a3)) + ((a4 + a5) + (a6 + a7));
    qhat[(size_t)n * QD + col] = r;
}

// ---------------- K8: finalize edw / context_new / out_context ----------------
// qhat aliases outctx_out (same-thread read-then-write) -> no __restrict__ on those.
__global__ void k_fin(const float* __restrict__ ema_dw, const float* __restrict__ ec,
                      const float* qhat, float* edw_out, float* ctxnew_out,
                      float* outctx_out) {
    size_t i = ((size_t)blockIdx.x * 256 + threadIdx.x) * 8;
    int n = (int)(i >> 11);
    float e = ec[n];
    float om = one_minus_decay();
#pragma unroll
    for (int h = 0; h < 2; ++h) {
        float4 dw = *(const float4*)(ema_dw + i + h * 4);
        float4 qh = *(const float4*)(qhat + i + h * 4);
        float4 ed, cn;
        ed.x = 0.99f * dw.x + om * qh.x; ed.y = 0.99f * dw.y + om * qh.y;
        ed.z = 0.99f * dw.z + om * qh.z; ed.w = 0.99f * dw.w + om * qh.w;
        cn.x = ed.x / e; cn.y = ed.y / e; cn.z = ed.z / e; cn.w = ed.w / e;
        *(float4*)(edw_out + i + h * 4) = ed;
        *(float4*)(ctxnew_out + i + h * 4) = cn;
        *(float4*)(outctx_out + i + h * 4) = cn;
    }
}

extern "C" void kernel_launch(void* const* d_in, const int* in_sizes, int n_in,
                              void* d_out, int out_size, void* d_ws, size_t ws_size,
                              hipStream_t stream) {
    const float* q         = (const float*)d_in[0];
    const float* ctx       = (const float*)d_in[1];
    const float* ema_count = (const float*)d_in[2];
    const float* ema_dw    = (const float*)d_in[3];

    float* out = (float*)d_out;
    float* o_qld    = out;                              // 16384
    float* o_outctx = out + BSZ;                        // 2097152
    float* o_ec     = o_outctx + (size_t)NCODES * QD;   // 1024
    float* o_edw    = o_ec + NCODES;                    // 2097152
    float* o_ctxnew = o_edw + (size_t)NCODES * QD;      // 2097152

    char* w = (char*)d_ws;
    float* ws_gsq   = (float*)w;                        // 1024 f
    int* ws_idx     = (int*)(w + 4096);                 // 16384 i
    int* ws_counts  = (int*)(w + 4096 + 65536);         // 1024 i
    int* ws_offsets = ws_counts + NCODES;               // 1024 i
    int* ws_list    = ws_offsets + NCODES;              // 16384 i

    // scratch carved from not-yet-written d_out regions:
    _Float16* gh = (_Float16*)o_ctxnew;                 // 4MB (dead after k_dist)
    _Float16* gl = gh + (size_t)NCODES * QD;            // 4MB
    float* pval  = o_edw;                               // 1MB (dead after k_merge)
    int*   pidx  = (int*)(o_edw + (size_t)NCOLG * BSZ); // 1MB
    float* qsq   = o_edw + (size_t)2 * NCOLG * BSZ;     // 64KB (dead after k_merge)
    int* chunkhist = (int*)o_outctx;                    // 256KB (dead after k_scan)
    int* basep     = chunkhist + NCHUNK * NCODES;       // 256KB (dead after k_fill)
    float* qhat    = o_outctx;                          // 8MB (finalized by k_fin)

    k_prep  <<<NCODES + BSZ / 4, 256, 0, stream>>>(ctx, q, gh, gl, ws_gsq, qsq);
    k_dist  <<<1024, 256, 0, stream>>>(q, gh, gl, ws_gsq, pval, pidx);
    k_merge <<<NCHUNK, 256, 0, stream>>>(pval, pidx, qsq, ws_idx, o_qld, chunkhist);
    k_scan  <<<1, 1024, 0, stream>>>(chunkhist, basep, ws_counts, ws_offsets, ema_count, o_ec);
    k_fill  <<<NCHUNK, 256, 0, stream>>>(ws_idx, basep, ws_offsets, ws_list);
    k_qhat  <<<dim3(NCODES, 8), 256, 0, stream>>>(q, ws_counts, ws_offsets, ws_list, qhat);
    k_fin   <<<NCODES * QD / 2048, 256, 0, stream>>>(ema_dw, o_ec, qhat,
                                                     o_edw, o_ctxnew, o_outctx);
}

// Round 17
// 225.648 us; speedup vs baseline: 1.4923x; 1.1655x over previous
//
#include <hip/hip_runtime.h>
#include <hip/hip_bf16.h>
#include <float.h>

#define BSZ 16384
#define NCODES 1024
#define QD 2048
#define NCHUNK 64   // BSZ / 256
#define NCOLG 16    // 8 col-blocks x 2 wc-waves

typedef _Float16 f16x8 __attribute__((ext_vector_type(8)));
typedef _Float16 f16x4 __attribute__((ext_vector_type(4)));
typedef float f32x4 __attribute__((ext_vector_type(4)));

static __device__ __forceinline__ float one_minus_decay() { return (float)(1.0 - 0.99); }

static __device__ __forceinline__ void async_copy16(const void* src, void* lds) {
    __builtin_amdgcn_global_load_lds((const __attribute__((address_space(1))) void*)src,
                                     (__attribute__((address_space(3))) void*)lds, 16, 0, 0);
}

// ---------------- K1: fused prep -- ctx -> fp16 hi + gsq (blocks 0..1023), qsq ----
// 1-term variant: gl is never consumed, so it is not computed or written.
__global__ void k_prep(const float* __restrict__ ctx, const float* __restrict__ q,
                       _Float16* __restrict__ gh, float* __restrict__ gsq,
                       float* __restrict__ qsq) {
    int tid = threadIdx.x;
    if (blockIdx.x < NCODES) {
        __shared__ float red[4];
        int n = blockIdx.x;
        float s = 0.f;
#pragma unroll
        for (int i = 0; i < 2; ++i) {
            int c = (tid + i * 256) * 4;
            float4 t = *(const float4*)(ctx + (size_t)n * QD + c);
            f16x4 h;
            h[0] = (_Float16)t.x; h[1] = (_Float16)t.y;
            h[2] = (_Float16)t.z; h[3] = (_Float16)t.w;
            *(f16x4*)(gh + (size_t)n * QD + c) = h;
            s += t.x * t.x + t.y * t.y + t.z * t.z + t.w * t.w;
        }
        for (int off = 32; off > 0; off >>= 1) s += __shfl_down(s, off);
        if ((tid & 63) == 0) red[tid >> 6] = s;
        __syncthreads();
        if (tid == 0) gsq[n] = red[0] + red[1] + red[2] + red[3];
    } else {
        int w = tid >> 6, lane = tid & 63;
        int b = (blockIdx.x - NCODES) * 4 + w;
        const float4* row = (const float4*)(q + (size_t)b * QD);
        float s = 0.f;
#pragma unroll
        for (int i = 0; i < 8; ++i) {
            float4 v = row[lane + i * 64];
            s += v.x * v.x + v.y * v.y + v.z * v.z + v.w * v.w;
        }
        for (int off = 32; off > 0; off >>= 1) s += __shfl_down(s, off);
        if (lane == 0) qsq[b] = s;
    }
}

// ---------------- K2: 1-TERM fp16 MFMA distance GEMM + per-tile argmin --------------
// r16 (2-term, 180us, absmax 0.039 = 5x under threshold) with the B-side lo term
// ALSO deleted: dot ~= qh.gh ; error = dq.g + qh.dg, sigma(dist) ~ 0.018 (sqrt(2)x
// r16) -> predicted absmax ~0.05-0.08, threshold 0.196. Gains: 32->16 MFMA/K-iter,
// B staging halved, LDS 48->32KB. Staging geometry/swizzle/sync byte-identical to
// the proven r5/r13 structure. (Ledger of measured regressions -- do NOT re-try:
// BK=32, dbuf-1barrier, 32x32 MFMA, qsq-fusion, stage-B-first, 512-thr, q-presplit
// at 128MB. Occupancy register-pinned at 2 blocks/CU.)
__launch_bounds__(256)
__global__ void k_dist(const float* __restrict__ q, const _Float16* __restrict__ gh,
                       const float* __restrict__ gsq,
                       float* __restrict__ pval, int* __restrict__ pidx) {
    __shared__ _Float16 ah[128][64];
    __shared__ _Float16 bh[128][64];

    const int tid = threadIdx.x;
    const int lane = tid & 63, wid = tid >> 6;
    const int wr = wid >> 1, wc = wid & 1;
    // XCD-chunked mapping: 8 col-blocks of one row-tile dispatch-adjacent on one XCD.
    const int n0 = blockIdx.x;
    const int xcd = n0 & 7, j = n0 >> 3;
    const int col = j & 7, rowt = xcd * 16 + (j >> 3);
    const int colBase = col * 128, rowBase = rowt * 128;
    const int fr = lane & 15, kg = lane >> 4;

    char* ahB = (char*)&ah[0][0];
    const char* bhB = (const char*)&bh[0][0];

    f32x4 acc[4][4];
#pragma unroll
    for (int m = 0; m < 4; ++m)
#pragma unroll
        for (int n = 0; n < 4; ++n) acc[m][n] = (f32x4)0.f;

    for (int kb = 0; kb < QD; kb += 64) {
        __syncthreads();
        // stage A: q fp32 -> fp16 (hi only), swizzled ds_write
#pragma unroll
        for (int s = 0; s < 8; ++s) {
            int f = s * 256 + tid;
            int row = f >> 4, k4 = (f & 15) * 4;
            float4 t = *(const float4*)(q + (size_t)(rowBase + row) * QD + kb + k4);
            f16x4 h;
            h[0] = (_Float16)t.x; h[1] = (_Float16)t.y;
            h[2] = (_Float16)t.z; h[3] = (_Float16)t.w;
            int byt = (row * 128 + k4 * 2) ^ ((row & 7) << 4);
            *(f16x4*)(ahB + byt) = h;
        }
        // stage B: linear LDS dest, inverse-swizzled per-lane global source (gh only)
#pragma unroll
        for (int i = 0; i < 4; ++i) {
            int g = wid * 4 + i;                 // 8-row group, 0..15
            int row = g * 8 + (lane >> 3);
            int gran = (lane & 7) ^ (lane >> 3); // 16B granule, pre-XORed
            size_t goff = (size_t)(colBase + row) * QD + kb + gran * 8;
            async_copy16(gh + goff, &bh[g * 8][0]);
        }
        __syncthreads();  // drains vmcnt (gload_lds) + lgkmcnt

#pragma unroll
        for (int h = 0; h < 2; ++h) {
            f16x8 a_h[4], b_h[4];
#pragma unroll
            for (int m = 0; m < 4; ++m) {
                int ar = wr * 64 + m * 16 + fr;
                int off = ar * 128 + ((h * 64 + kg * 16) ^ ((ar & 7) << 4));
                a_h[m] = *(const f16x8*)(ahB + off);
            }
#pragma unroll
            for (int n = 0; n < 4; ++n) {
                int br = wc * 64 + n * 16 + fr;
                int off = br * 128 + ((h * 64 + kg * 16) ^ ((br & 7) << 4));
                b_h[n] = *(const f16x8*)(bhB + off);
            }
#pragma unroll
            for (int m = 0; m < 4; ++m)
#pragma unroll
                for (int n = 0; n < 4; ++n)
                    acc[m][n] = __builtin_amdgcn_mfma_f32_16x16x32_f16(a_h[m], b_h[n], acc[m][n], 0, 0, 0);
        }
    }

    // epilogue: d = gsq - 2*dot; per-row argmin (first-occurrence ties)
    float mv[4][4]; int mi[4][4];
#pragma unroll
    for (int m = 0; m < 4; ++m)
#pragma unroll
        for (int r = 0; r < 4; ++r) { mv[m][r] = FLT_MAX; mi[m][r] = 0x7fffffff; }
#pragma unroll
    for (int n = 0; n < 4; ++n) {
        int c = colBase + wc * 64 + n * 16 + fr;
        float gq = gsq[c];
#pragma unroll
        for (int m = 0; m < 4; ++m)
#pragma unroll
            for (int r = 0; r < 4; ++r) {
                float d = gq - 2.0f * acc[m][n][r];
                if (d < mv[m][r]) { mv[m][r] = d; mi[m][r] = c; }
            }
    }
#pragma unroll
    for (int off = 1; off < 16; off <<= 1) {
#pragma unroll
        for (int m = 0; m < 4; ++m)
#pragma unroll
            for (int r = 0; r < 4; ++r) {
                float ov = __shfl_xor(mv[m][r], off);
                int   oi = __shfl_xor(mi[m][r], off);
                if (ov < mv[m][r] || (ov == mv[m][r] && oi < mi[m][r])) { mv[m][r] = ov; mi[m][r] = oi; }
            }
    }
    if (fr == 0) {
        const size_t slot = (size_t)(col * 2 + wc) * BSZ;
#pragma unroll
        for (int m = 0; m < 4; ++m)
#pragma unroll
            for (int r = 0; r < 4; ++r) {
                int grow = rowBase + wr * 64 + m * 16 + kg * 4 + r;
                pval[slot + grow] = mv[m][r];
                pidx[slot + grow] = mi[m][r];
            }
    }
}

// ---------------- K3: merge 16 partials -> argmin + fused qld + fused chunk-hist ----
__global__ void k_merge(const float* __restrict__ pval, const int* __restrict__ pidx,
                        const float* __restrict__ qsq,
                        int* __restrict__ idx_out, float* __restrict__ qld,
                        int* __restrict__ chunkhist) {
    __shared__ int h[NCODES];
    int c = blockIdx.x, tid = threadIdx.x;
    int b = c * 256 + tid;
#pragma unroll
    for (int s = 0; s < 4; ++s) h[tid + s * 256] = 0;
    float bv = pval[b]; int bi = pidx[b];
    for (int y = 1; y < NCOLG; ++y) {
        float v = pval[(size_t)y * BSZ + b]; int ii = pidx[(size_t)y * BSZ + b];
        if (v < bv || (v == bv && ii < bi)) { bv = v; bi = ii; }
    }
    idx_out[b] = bi;
    qld[b] = (qsq[b] + bv) * (1.0f / (float)QD);
    __syncthreads();
    atomicAdd(&h[bi], 1);
    __syncthreads();
#pragma unroll
    for (int s = 0; s < 4; ++s) chunkhist[c * NCODES + tid + s * 256] = h[tid + s * 256];
}

// ---------------- K4: scan (counting sort) + fused ec ----------------
__global__ void k_scan(const int* __restrict__ chunkhist, int* __restrict__ base,
                       int* __restrict__ counts, int* __restrict__ offsets,
                       const float* __restrict__ ema_count, float* __restrict__ ec_out) {
    __shared__ int s[NCODES];
    __shared__ float e2[NCODES];
    int code = threadIdx.x;  // 1024 threads
    int run = 0;
    for (int c = 0; c < NCHUNK; ++c) {
        base[c * NCODES + code] = run;
        run += chunkhist[c * NCODES + code];
    }
    counts[code] = run;
    s[code] = run; __syncthreads();
    for (int off = 1; off < NCODES; off <<= 1) {
        int v = (code >= off) ? s[code - off] : 0;
        __syncthreads();
        s[code] += v; __syncthreads();
    }
    offsets[code] = s[code] - run;
    float er = 0.99f * ema_count[code] + one_minus_decay() * (float)run;
    e2[code] = er; __syncthreads();
    for (int off = 512; off > 0; off >>= 1) {
        if (code < off) e2[code] += e2[code + off];
        __syncthreads();
    }
    float n = e2[0];
    ec_out[code] = (er + 1e-5f) / (n + (float)(2048.0 * 1e-5)) * n;
}

__global__ void k_fill(const int* __restrict__ idx, const int* __restrict__ base,
                       const int* __restrict__ offsets, int* __restrict__ list) {
    __shared__ int sidx[256];
    int c = blockIdx.x, tid = threadIdx.x;
    int b = c * 256 + tid;
    int n = idx[b];
    sidx[tid] = n; __syncthreads();
    int rank = 0;
    for (int j = 0; j < tid; ++j) rank += (sidx[j] == n);
    list[offsets[n] + base[c * NCODES + n] + rank] = b;
}

// ---------------- K6: q_hat segment-sum, parallel over (code, col-group) ----------------
__global__ void k_qhat(const float* __restrict__ q, const int* __restrict__ counts,
                       const int* __restrict__ offsets, const int* __restrict__ list,
                       float* __restrict__ qhat) {
    int n = blockIdx.x;
    int col = blockIdx.y * 256 + threadIdx.x;
    int cnt = counts[n];
    const int* lp = list + offsets[n];
    float a0 = 0.f, a1 = 0.f, a2 = 0.f, a3 = 0.f, a4 = 0.f, a5 = 0.f, a6 = 0.f, a7 = 0.f;
    int i = 0;
    for (; i + 8 <= cnt; i += 8) {
        int b0 = lp[i], b1 = lp[i + 1], b2 = lp[i + 2], b3 = lp[i + 3];
        int b4 = lp[i + 4], b5 = lp[i + 5], b6 = lp[i + 6], b7 = lp[i + 7];
        a0 += q[(size_t)b0 * QD + col]; a1 += q[(size_t)b1 * QD + col];
        a2 += q[(size_t)b2 * QD + col]; a3 += q[(size_t)b3 * QD + col];
        a4 += q[(size_t)b4 * QD + col]; a5 += q[(size_t)b5 * QD + col];
        a6 += q[(size_t)b6 * QD + col]; a7 += q[(size_t)b7 * QD + col];
    }
    for (; i < cnt; ++i) a0 += q[(size_t)lp[i] * QD + col];
    float r = ((a0 + a1) + (a2 + a3)) + ((a4 + a5) + (a6 + a7));
    qhat[(size_t)n * QD + col] = r;
}

// ---------------- K8: finalize edw / context_new / out_context ----------------
// qhat aliases outctx_out (same-thread read-then-write) -> no __restrict__ on those.
__global__ void k_fin(const float* __restrict__ ema_dw, const float* __restrict__ ec,
                      const float* qhat, float* edw_out, float* ctxnew_out,
                      float* outctx_out) {
    size_t i = ((size_t)blockIdx.x * 256 + threadIdx.x) * 8;
    int n = (int)(i >> 11);
    float e = ec[n];
    float om = one_minus_decay();
#pragma unroll
    for (int h = 0; h < 2; ++h) {
        float4 dw = *(const float4*)(ema_dw + i + h * 4);
        float4 qh = *(const float4*)(qhat + i + h * 4);
        float4 ed, cn;
        ed.x = 0.99f * dw.x + om * qh.x; ed.y = 0.99f * dw.y + om * qh.y;
        ed.z = 0.99f * dw.z + om * qh.z; ed.w = 0.99f * dw.w + om * qh.w;
        cn.x = ed.x / e; cn.y = ed.y / e; cn.z = ed.z / e; cn.w = ed.w / e;
        *(float4*)(edw_out + i + h * 4) = ed;
        *(float4*)(ctxnew_out + i + h * 4) = cn;
        *(float4*)(outctx_out + i + h * 4) = cn;
    }
}

extern "C" void kernel_launch(void* const* d_in, const int* in_sizes, int n_in,
                              void* d_out, int out_size, void* d_ws, size_t ws_size,
                              hipStream_t stream) {
    const float* q         = (const float*)d_in[0];
    const float* ctx       = (const float*)d_in[1];
    const float* ema_count = (const float*)d_in[2];
    const float* ema_dw    = (const float*)d_in[3];

    float* out = (float*)d_out;
    float* o_qld    = out;                              // 16384
    float* o_outctx = out + BSZ;                        // 2097152
    float* o_ec     = o_outctx + (size_t)NCODES * QD;   // 1024
    float* o_edw    = o_ec + NCODES;                    // 2097152
    float* o_ctxnew = o_edw + (size_t)NCODES * QD;      // 2097152

    char* w = (char*)d_ws;
    float* ws_gsq   = (float*)w;                        // 1024 f
    int* ws_idx     = (int*)(w + 4096);                 // 16384 i
    int* ws_counts  = (int*)(w + 4096 + 65536);         // 1024 i
    int* ws_offsets = ws_counts + NCODES;               // 1024 i
    int* ws_list    = ws_offsets + NCODES;              // 16384 i

    // scratch carved from not-yet-written d_out regions:
    _Float16* gh = (_Float16*)o_ctxnew;                 // 4MB (dead after k_dist)
    float* pval  = o_edw;                               // 1MB (dead after k_merge)
    int*   pidx  = (int*)(o_edw + (size_t)NCOLG * BSZ); // 1MB
    float* qsq   = o_edw + (size_t)2 * NCOLG * BSZ;     // 64KB (dead after k_merge)
    int* chunkhist = (int*)o_outctx;                    // 256KB (dead after k_scan)
    int* basep     = chunkhist + NCHUNK * NCODES;       // 256KB (dead after k_fill)
    float* qhat    = o_outctx;                          // 8MB (finalized by k_fin)

    k_prep  <<<NCODES + BSZ / 4, 256, 0, stream>>>(ctx, q, gh, ws_gsq, qsq);
    k_dist  <<<1024, 256, 0, stream>>>(q, gh, ws_gsq, pval, pidx);
    k_merge <<<NCHUNK, 256, 0, stream>>>(pval, pidx, qsq, ws_idx, o_qld, chunkhist);
    k_scan  <<<1, 1024, 0, stream>>>(chunkhist, basep, ws_counts, ws_offsets, ema_count, o_ec);
    k_fill  <<<NCHUNK, 256, 0, stream>>>(ws_idx, basep, ws_offsets, ws_list);
    k_qhat  <<<dim3(NCODES, 8), 256, 0, stream>>>(q, ws_counts, ws_offsets, ws_list, qhat);
    k_fin   <<<NCODES * QD / 2048, 256, 0, stream>>>(ema_dw, o_ec, qhat,
                                                     o_edw, o_ctxnew, o_outctx);
}

// Round 18
// 212.376 us; speedup vs baseline: 1.5856x; 1.0625x over previous
//
#include <hip/hip_runtime.h>
#include <hip/hip_bf16.h>
#include <float.h>

#define BSZ 16384
#define NCODES 1024
#define QD 2048
#define NCHUNK 64   // BSZ / 256
#define NCOLG 16    // 8 col-blocks x 2 wc-waves

typedef _Float16 f16x8 __attribute__((ext_vector_type(8)));
typedef _Float16 f16x4 __attribute__((ext_vector_type(4)));
typedef float f32x4 __attribute__((ext_vector_type(4)));

static __device__ __forceinline__ float one_minus_decay() { return (float)(1.0 - 0.99); }

static __device__ __forceinline__ void async_copy16(const void* src, void* lds) {
    __builtin_amdgcn_global_load_lds((const __attribute__((address_space(1))) void*)src,
                                     (__attribute__((address_space(3))) void*)lds, 16, 0, 0);
}

// ---------------- K1a: unified prep -- EVERY row (ctx then q) -> fp16 hi + norm ----
// One 2048-elem row per block, 256 thr x 8 elems. Same cvt math as r17 (bit-identical
// distances -> absmax unchanged at 0.051).
__global__ void k_prep_all(const float* __restrict__ ctx, const float* __restrict__ q,
                           _Float16* __restrict__ gh, float* __restrict__ gsq,
                           _Float16* __restrict__ qh, float* __restrict__ qsq) {
    __shared__ float red[4];
    int tid = threadIdx.x;
    const float* src; _Float16* dh; float* nrm;
    if (blockIdx.x < NCODES) {
        size_t n = blockIdx.x;
        src = ctx + n * QD; dh = gh + n * QD; nrm = gsq + n;
    } else {
        size_t b = blockIdx.x - NCODES;
        src = q + b * QD; dh = qh + b * QD; nrm = qsq + b;
    }
    int c = tid * 8;
    float4 t0 = *(const float4*)(src + c);
    float4 t1 = *(const float4*)(src + c + 4);
    float s = t0.x * t0.x + t0.y * t0.y + t0.z * t0.z + t0.w * t0.w
            + t1.x * t1.x + t1.y * t1.y + t1.z * t1.z + t1.w * t1.w;
    f16x8 h;
    h[0] = (_Float16)t0.x; h[1] = (_Float16)t0.y;
    h[2] = (_Float16)t0.z; h[3] = (_Float16)t0.w;
    h[4] = (_Float16)t1.x; h[5] = (_Float16)t1.y;
    h[6] = (_Float16)t1.z; h[7] = (_Float16)t1.w;
    *(f16x8*)(dh + c) = h;
    for (int off = 32; off > 0; off >>= 1) s += __shfl_down(s, off);
    if ((tid & 63) == 0) red[tid >> 6] = s;
    __syncthreads();
    if (tid == 0) *nrm = red[0] + red[1] + red[2] + red[3];
}

// ---------------- K1b: r17 fallback prep (if ws too small for qh) ----------------
__global__ void k_prep_r17(const float* __restrict__ ctx, const float* __restrict__ q,
                           _Float16* __restrict__ gh, float* __restrict__ gsq,
                           float* __restrict__ qsq) {
    int tid = threadIdx.x;
    if (blockIdx.x < NCODES) {
        __shared__ float red[4];
        int n = blockIdx.x;
        float s = 0.f;
#pragma unroll
        for (int i = 0; i < 2; ++i) {
            int c = (tid + i * 256) * 4;
            float4 t = *(const float4*)(ctx + (size_t)n * QD + c);
            f16x4 h;
            h[0] = (_Float16)t.x; h[1] = (_Float16)t.y;
            h[2] = (_Float16)t.z; h[3] = (_Float16)t.w;
            *(f16x4*)(gh + (size_t)n * QD + c) = h;
            s += t.x * t.x + t.y * t.y + t.z * t.z + t.w * t.w;
        }
        for (int off = 32; off > 0; off >>= 1) s += __shfl_down(s, off);
        if ((tid & 63) == 0) red[tid >> 6] = s;
        __syncthreads();
        if (tid == 0) gsq[n] = red[0] + red[1] + red[2] + red[3];
    } else {
        int w = tid >> 6, lane = tid & 63;
        int b = (blockIdx.x - NCODES) * 4 + w;
        const float4* row = (const float4*)(q + (size_t)b * QD);
        float s = 0.f;
#pragma unroll
        for (int i = 0; i < 8; ++i) {
            float4 v = row[lane + i * 64];
            s += v.x * v.x + v.y * v.y + v.z * v.z + v.w * v.w;
        }
        for (int off = 32; off > 0; off >>= 1) s += __shfl_down(s, off);
        if (lane == 0) qsq[b] = s;
    }
}

// ---------------- K2a: 1-term fp16 GEMM, BOTH operands pre-split + gload_lds --------
// r17's 145us kernel with stage A replaced by the r15-VALIDATED async mirror of
// stage B (identical geometry: linear LDS dest + inverse-swizzled per-lane source).
// Deletes the in-loop q->fp16 cvt (was 36.5% VALUBusy) and halves stage-A bytes.
// Per K-iter: 8 gload_lds (16KB) | barrier | 16 ds_read_b128 + 16 MFMA | barrier.
// (Ledger -- do NOT re-try: BK=32, dbuf-1barrier, 32x32 MFMA, qsq-fusion,
//  stage-B-first, 512-thr. Occupancy register-pinned at 2 blocks/CU.)
__launch_bounds__(256)
__global__ void k_dist_pre(const _Float16* __restrict__ qh, const _Float16* __restrict__ gh,
                           const float* __restrict__ gsq,
                           float* __restrict__ pval, int* __restrict__ pidx) {
    __shared__ _Float16 ah[128][64];
    __shared__ _Float16 bh[128][64];

    const int tid = threadIdx.x;
    const int lane = tid & 63, wid = tid >> 6;
    const int wr = wid >> 1, wc = wid & 1;
    // XCD-chunked mapping: 8 col-blocks of one row-tile dispatch-adjacent on one XCD.
    const int n0 = blockIdx.x;
    const int xcd = n0 & 7, j = n0 >> 3;
    const int col = j & 7, rowt = xcd * 16 + (j >> 3);
    const int colBase = col * 128, rowBase = rowt * 128;
    const int fr = lane & 15, kg = lane >> 4;

    char* ahB = (char*)&ah[0][0];
    const char* bhB = (const char*)&bh[0][0];

    // staging geometry (r5-proven): 8-row group, pre-XORed 16B granule
    const int srow = lane >> 3;
    const int gran = (lane & 7) ^ (lane >> 3);

    f32x4 acc[4][4];
#pragma unroll
    for (int m = 0; m < 4; ++m)
#pragma unroll
        for (int n = 0; n < 4; ++n) acc[m][n] = (f32x4)0.f;

    for (int kb = 0; kb < QD; kb += 64) {
        __syncthreads();
        // stage A: async from qh (mirror of stage B)
#pragma unroll
        for (int i = 0; i < 4; ++i) {
            int g = wid * 4 + i;
            size_t aoff = (size_t)(rowBase + g * 8 + srow) * QD + kb + gran * 8;
            async_copy16(qh + aoff, &ah[g * 8][0]);
        }
        // stage B: async from gh
#pragma unroll
        for (int i = 0; i < 4; ++i) {
            int g = wid * 4 + i;
            size_t goff = (size_t)(colBase + g * 8 + srow) * QD + kb + gran * 8;
            async_copy16(gh + goff, &bh[g * 8][0]);
        }
        __syncthreads();  // drains vmcnt (gload_lds)

#pragma unroll
        for (int h = 0; h < 2; ++h) {
            f16x8 a_h[4], b_h[4];
#pragma unroll
            for (int m = 0; m < 4; ++m) {
                int ar = wr * 64 + m * 16 + fr;
                int off = ar * 128 + ((h * 64 + kg * 16) ^ ((ar & 7) << 4));
                a_h[m] = *(const f16x8*)(ahB + off);
            }
#pragma unroll
            for (int n = 0; n < 4; ++n) {
                int br = wc * 64 + n * 16 + fr;
                int off = br * 128 + ((h * 64 + kg * 16) ^ ((br & 7) << 4));
                b_h[n] = *(const f16x8*)(bhB + off);
            }
#pragma unroll
            for (int m = 0; m < 4; ++m)
#pragma unroll
                for (int n = 0; n < 4; ++n)
                    acc[m][n] = __builtin_amdgcn_mfma_f32_16x16x32_f16(a_h[m], b_h[n], acc[m][n], 0, 0, 0);
        }
    }

    // epilogue: d = gsq - 2*dot; per-row argmin (first-occurrence ties)
    float mv[4][4]; int mi[4][4];
#pragma unroll
    for (int m = 0; m < 4; ++m)
#pragma unroll
        for (int r = 0; r < 4; ++r) { mv[m][r] = FLT_MAX; mi[m][r] = 0x7fffffff; }
#pragma unroll
    for (int n = 0; n < 4; ++n) {
        int c = colBase + wc * 64 + n * 16 + fr;
        float gq = gsq[c];
#pragma unroll
        for (int m = 0; m < 4; ++m)
#pragma unroll
            for (int r = 0; r < 4; ++r) {
                float d = gq - 2.0f * acc[m][n][r];
                if (d < mv[m][r]) { mv[m][r] = d; mi[m][r] = c; }
            }
    }
#pragma unroll
    for (int off = 1; off < 16; off <<= 1) {
#pragma unroll
        for (int m = 0; m < 4; ++m)
#pragma unroll
            for (int r = 0; r < 4; ++r) {
                float ov = __shfl_xor(mv[m][r], off);
                int   oi = __shfl_xor(mi[m][r], off);
                if (ov < mv[m][r] || (ov == mv[m][r] && oi < mi[m][r])) { mv[m][r] = ov; mi[m][r] = oi; }
            }
    }
    if (fr == 0) {
        const size_t slot = (size_t)(col * 2 + wc) * BSZ;
#pragma unroll
        for (int m = 0; m < 4; ++m)
#pragma unroll
            for (int r = 0; r < 4; ++r) {
                int grow = rowBase + wr * 64 + m * 16 + kg * 4 + r;
                pval[slot + grow] = mv[m][r];
                pidx[slot + grow] = mi[m][r];
            }
    }
}

// ---------------- K2b: r17 fallback GEMM (in-loop q cvt) -- measured 145us ----------
__launch_bounds__(256)
__global__ void k_dist_r17(const float* __restrict__ q, const _Float16* __restrict__ gh,
                           const float* __restrict__ gsq,
                           float* __restrict__ pval, int* __restrict__ pidx) {
    __shared__ _Float16 ah[128][64];
    __shared__ _Float16 bh[128][64];

    const int tid = threadIdx.x;
    const int lane = tid & 63, wid = tid >> 6;
    const int wr = wid >> 1, wc = wid & 1;
    const int n0 = blockIdx.x;
    const int xcd = n0 & 7, j = n0 >> 3;
    const int col = j & 7, rowt = xcd * 16 + (j >> 3);
    const int colBase = col * 128, rowBase = rowt * 128;
    const int fr = lane & 15, kg = lane >> 4;

    char* ahB = (char*)&ah[0][0];
    const char* bhB = (const char*)&bh[0][0];

    f32x4 acc[4][4];
#pragma unroll
    for (int m = 0; m < 4; ++m)
#pragma unroll
        for (int n = 0; n < 4; ++n) acc[m][n] = (f32x4)0.f;

    for (int kb = 0; kb < QD; kb += 64) {
        __syncthreads();
#pragma unroll
        for (int s = 0; s < 8; ++s) {
            int f = s * 256 + tid;
            int row = f >> 4, k4 = (f & 15) * 4;
            float4 t = *(const float4*)(q + (size_t)(rowBase + row) * QD + kb + k4);
            f16x4 h;
            h[0] = (_Float16)t.x; h[1] = (_Float16)t.y;
            h[2] = (_Float16)t.z; h[3] = (_Float16)t.w;
            int byt = (row * 128 + k4 * 2) ^ ((row & 7) << 4);
            *(f16x4*)(ahB + byt) = h;
        }
#pragma unroll
        for (int i = 0; i < 4; ++i) {
            int g = wid * 4 + i;
            int row = g * 8 + (lane >> 3);
            int gran = (lane & 7) ^ (lane >> 3);
            size_t goff = (size_t)(colBase + row) * QD + kb + gran * 8;
            async_copy16(gh + goff, &bh[g * 8][0]);
        }
        __syncthreads();

#pragma unroll
        for (int h = 0; h < 2; ++h) {
            f16x8 a_h[4], b_h[4];
#pragma unroll
            for (int m = 0; m < 4; ++m) {
                int ar = wr * 64 + m * 16 + fr;
                int off = ar * 128 + ((h * 64 + kg * 16) ^ ((ar & 7) << 4));
                a_h[m] = *(const f16x8*)(ahB + off);
            }
#pragma unroll
            for (int n = 0; n < 4; ++n) {
                int br = wc * 64 + n * 16 + fr;
                int off = br * 128 + ((h * 64 + kg * 16) ^ ((br & 7) << 4));
                b_h[n] = *(const f16x8*)(bhB + off);
            }
#pragma unroll
            for (int m = 0; m < 4; ++m)
#pragma unroll
                for (int n = 0; n < 4; ++n)
                    acc[m][n] = __builtin_amdgcn_mfma_f32_16x16x32_f16(a_h[m], b_h[n], acc[m][n], 0, 0, 0);
        }
    }

    float mv[4][4]; int mi[4][4];
#pragma unroll
    for (int m = 0; m < 4; ++m)
#pragma unroll
        for (int r = 0; r < 4; ++r) { mv[m][r] = FLT_MAX; mi[m][r] = 0x7fffffff; }
#pragma unroll
    for (int n = 0; n < 4; ++n) {
        int c = colBase + wc * 64 + n * 16 + fr;
        float gq = gsq[c];
#pragma unroll
        for (int m = 0; m < 4; ++m)
#pragma unroll
            for (int r = 0; r < 4; ++r) {
                float d = gq - 2.0f * acc[m][n][r];
                if (d < mv[m][r]) { mv[m][r] = d; mi[m][r] = c; }
            }
    }
#pragma unroll
    for (int off = 1; off < 16; off <<= 1) {
#pragma unroll
        for (int m = 0; m < 4; ++m)
#pragma unroll
            for (int r = 0; r < 4; ++r) {
                float ov = __shfl_xor(mv[m][r], off);
                int   oi = __shfl_xor(mi[m][r], off);
                if (ov < mv[m][r] || (ov == mv[m][r] && oi < mi[m][r])) { mv[m][r] = ov; mi[m][r] = oi; }
            }
    }
    if (fr == 0) {
        const size_t slot = (size_t)(col * 2 + wc) * BSZ;
#pragma unroll
        for (int m = 0; m < 4; ++m)
#pragma unroll
            for (int r = 0; r < 4; ++r) {
                int grow = rowBase + wr * 64 + m * 16 + kg * 4 + r;
                pval[slot + grow] = mv[m][r];
                pidx[slot + grow] = mi[m][r];
            }
    }
}

// ---------------- K3: merge 16 partials -> argmin + fused qld + fused chunk-hist ----
__global__ void k_merge(const float* __restrict__ pval, const int* __restrict__ pidx,
                        const float* __restrict__ qsq,
                        int* __restrict__ idx_out, float* __restrict__ qld,
                        int* __restrict__ chunkhist) {
    __shared__ int h[NCODES];
    int c = blockIdx.x, tid = threadIdx.x;
    int b = c * 256 + tid;
#pragma unroll
    for (int s = 0; s < 4; ++s) h[tid + s * 256] = 0;
    float bv = pval[b]; int bi = pidx[b];
    for (int y = 1; y < NCOLG; ++y) {
        float v = pval[(size_t)y * BSZ + b]; int ii = pidx[(size_t)y * BSZ + b];
        if (v < bv || (v == bv && ii < bi)) { bv = v; bi = ii; }
    }
    idx_out[b] = bi;
    qld[b] = (qsq[b] + bv) * (1.0f / (float)QD);
    __syncthreads();
    atomicAdd(&h[bi], 1);
    __syncthreads();
#pragma unroll
    for (int s = 0; s < 4; ++s) chunkhist[c * NCODES + tid + s * 256] = h[tid + s * 256];
}

// ---------------- K4: scan (counting sort) + fused ec ----------------
__global__ void k_scan(const int* __restrict__ chunkhist, int* __restrict__ base,
                       int* __restrict__ counts, int* __restrict__ offsets,
                       const float* __restrict__ ema_count, float* __restrict__ ec_out) {
    __shared__ int s[NCODES];
    __shared__ float e2[NCODES];
    int code = threadIdx.x;  // 1024 threads
    int run = 0;
    for (int c = 0; c < NCHUNK; ++c) {
        base[c * NCODES + code] = run;
        run += chunkhist[c * NCODES + code];
    }
    counts[code] = run;
    s[code] = run; __syncthreads();
    for (int off = 1; off < NCODES; off <<= 1) {
        int v = (code >= off) ? s[code - off] : 0;
        __syncthreads();
        s[code] += v; __syncthreads();
    }
    offsets[code] = s[code] - run;
    float er = 0.99f * ema_count[code] + one_minus_decay() * (float)run;
    e2[code] = er; __syncthreads();
    for (int off = 512; off > 0; off >>= 1) {
        if (code < off) e2[code] += e2[code + off];
        __syncthreads();
    }
    float n = e2[0];
    ec_out[code] = (er + 1e-5f) / (n + (float)(2048.0 * 1e-5)) * n;
}

__global__ void k_fill(const int* __restrict__ idx, const int* __restrict__ base,
                       const int* __restrict__ offsets, int* __restrict__ list) {
    __shared__ int sidx[256];
    int c = blockIdx.x, tid = threadIdx.x;
    int b = c * 256 + tid;
    int n = idx[b];
    sidx[tid] = n; __syncthreads();
    int rank = 0;
    for (int j = 0; j < tid; ++j) rank += (sidx[j] == n);
    list[offsets[n] + base[c * NCODES + n] + rank] = b;
}

// ---------------- K6: q_hat segment-sum, parallel over (code, col-group) ----------------
__global__ void k_qhat(const float* __restrict__ q, const int* __restrict__ counts,
                       const int* __restrict__ offsets, const int* __restrict__ list,
                       float* __restrict__ qhat) {
    int n = blockIdx.x;
    int col = blockIdx.y * 256 + threadIdx.x;
    int cnt = counts[n];
    const int* lp = list + offsets[n];
    float a0 = 0.f, a1 = 0.f, a2 = 0.f, a3 = 0.f, a4 = 0.f, a5 = 0.f, a6 = 0.f, a7 = 0.f;
    int i = 0;
    for (; i + 8 <= cnt; i += 8) {
        int b0 = lp[i], b1 = lp[i + 1], b2 = lp[i + 2], b3 = lp[i + 3];
        int b4 = lp[i + 4], b5 = lp[i + 5], b6 = lp[i + 6], b7 = lp[i + 7];
        a0 += q[(size_t)b0 * QD + col]; a1 += q[(size_t)b1 * QD + col];
        a2 += q[(size_t)b2 * QD + col]; a3 += q[(size_t)b3 * QD + col];
        a4 += q[(size_t)b4 * QD + col]; a5 += q[(size_t)b5 * QD + col];
        a6 += q[(size_t)b6 * QD + col]; a7 += q[(size_t)b7 * QD + col];
    }
    for (; i < cnt; ++i) a0 += q[(size_t)lp[i] * QD + col];
    float r = ((a0 + a1) + (a2 + a3)) + ((a4 + a5) + (a6 + a7));
    qhat[(size_t)n * QD + col] = r;
}

// ---------------- K8: finalize edw / context_new / out_context ----------------
// qhat aliases outctx_out (same-thread read-then-write) -> no __restrict__ on those.
__global__ void k_fin(const float* __restrict__ ema_dw, const float* __restrict__ ec,
                      const float* qhat, float* edw_out, float* ctxnew_out,
                      float* outctx_out) {
    size_t i = ((size_t)blockIdx.x * 256 + threadIdx.x) * 8;
    int n = (int)(i >> 11);
    float e = ec[n];
    float om = one_minus_decay();
#pragma unroll
    for (int h = 0; h < 2; ++h) {
        float4 dw = *(const float4*)(ema_dw + i + h * 4);
        float4 qh = *(const float4*)(qhat + i + h * 4);
        float4 ed, cn;
        ed.x = 0.99f * dw.x + om * qh.x; ed.y = 0.99f * dw.y + om * qh.y;
        ed.z = 0.99f * dw.z + om * qh.z; ed.w = 0.99f * dw.w + om * qh.w;
        cn.x = ed.x / e; cn.y = ed.y / e; cn.z = ed.z / e; cn.w = ed.w / e;
        *(float4*)(edw_out + i + h * 4) = ed;
        *(float4*)(ctxnew_out + i + h * 4) = cn;
        *(float4*)(outctx_out + i + h * 4) = cn;
    }
}

extern "C" void kernel_launch(void* const* d_in, const int* in_sizes, int n_in,
                              void* d_out, int out_size, void* d_ws, size_t ws_size,
                              hipStream_t stream) {
    const float* q         = (const float*)d_in[0];
    const float* ctx       = (const float*)d_in[1];
    const float* ema_count = (const float*)d_in[2];
    const float* ema_dw    = (const float*)d_in[3];

    float* out = (float*)d_out;
    float* o_qld    = out;                              // 16384
    float* o_outctx = out + BSZ;                        // 2097152
    float* o_ec     = o_outctx + (size_t)NCODES * QD;   // 1024
    float* o_edw    = o_ec + NCODES;                    // 2097152
    float* o_ctxnew = o_edw + (size_t)NCODES * QD;      // 2097152

    char* w = (char*)d_ws;
    float* ws_gsq   = (float*)w;                        // 1024 f
    int* ws_idx     = (int*)(w + 4096);                 // 16384 i
    int* ws_counts  = (int*)(w + 4096 + 65536);         // 1024 i
    int* ws_offsets = ws_counts + NCODES;               // 1024 i
    int* ws_list    = ws_offsets + NCODES;              // 16384 i

    // qh pre-split scratch (64 MB) at ws + 1MB, if available
    const size_t presplit_need = (size_t)1048576 + (size_t)BSZ * QD * sizeof(_Float16);
    const bool use_pre = (ws_size >= presplit_need);
    _Float16* qh = (_Float16*)(w + 1048576);

    // scratch carved from not-yet-written d_out regions:
    _Float16* gh = (_Float16*)o_ctxnew;                 // 4MB (dead after k_dist)
    float* pval  = o_edw;                               // 1MB (dead after k_merge)
    int*   pidx  = (int*)(o_edw + (size_t)NCOLG * BSZ); // 1MB
    float* qsq   = o_edw + (size_t)2 * NCOLG * BSZ;     // 64KB (dead after k_merge)
    int* chunkhist = (int*)o_outctx;                    // 256KB (dead after k_scan)
    int* basep     = chunkhist + NCHUNK * NCODES;       // 256KB (dead after k_fill)
    float* qhat    = o_outctx;                          // 8MB (finalized by k_fin)

    if (use_pre) {
        k_prep_all<<<NCODES + BSZ, 256, 0, stream>>>(ctx, q, gh, ws_gsq, qh, qsq);
        k_dist_pre<<<1024, 256, 0, stream>>>(qh, gh, ws_gsq, pval, pidx);
    } else {
        k_prep_r17<<<NCODES + BSZ / 4, 256, 0, stream>>>(ctx, q, gh, ws_gsq, qsq);
        k_dist_r17<<<1024, 256, 0, stream>>>(q, gh, ws_gsq, pval, pidx);
    }
    k_merge <<<NCHUNK, 256, 0, stream>>>(pval, pidx, qsq, ws_idx, o_qld, chunkhist);
    k_scan  <<<1, 1024, 0, stream>>>(chunkhist, basep, ws_counts, ws_offsets, ema_count, o_ec);
    k_fill  <<<NCHUNK, 256, 0, stream>>>(ws_idx, basep, ws_offsets, ws_list);
    k_qhat  <<<dim3(NCODES, 8), 256, 0, stream>>>(q, ws_counts, ws_offsets, ws_list, qhat);
    k_fin   <<<NCODES * QD / 2048, 256, 0, stream>>>(ema_dw, o_ec, qhat,
                                                     o_edw, o_ctxnew, o_outctx);
}

// Round 19
// 200.936 us; speedup vs baseline: 1.6759x; 1.0569x over previous
//
#include <hip/hip_runtime.h>
#include <hip/hip_bf16.h>
#include <float.h>

#define BSZ 16384
#define NCODES 1024
#define QD 2048
#define NCHUNK 64   // BSZ / 256
#define NCOLG 16    // 8 col-blocks x 2 wc-waves

typedef _Float16 f16x8 __attribute__((ext_vector_type(8)));
typedef _Float16 f16x4 __attribute__((ext_vector_type(4)));
typedef float f32x4 __attribute__((ext_vector_type(4)));

static __device__ __forceinline__ float one_minus_decay() { return (float)(1.0 - 0.99); }

static __device__ __forceinline__ void async_copy16(const void* src, void* lds) {
    __builtin_amdgcn_global_load_lds((const __attribute__((address_space(1))) void*)src,
                                     (__attribute__((address_space(3))) void*)lds, 16, 0, 0);
}

// ---------------- K1a: unified prep -- EVERY row (ctx then q) -> fp16 hi + norm ----
__global__ void k_prep_all(const float* __restrict__ ctx, const float* __restrict__ q,
                           _Float16* __restrict__ gh, float* __restrict__ gsq,
                           _Float16* __restrict__ qh, float* __restrict__ qsq) {
    __shared__ float red[4];
    int tid = threadIdx.x;
    const float* src; _Float16* dh; float* nrm;
    if (blockIdx.x < NCODES) {
        size_t n = blockIdx.x;
        src = ctx + n * QD; dh = gh + n * QD; nrm = gsq + n;
    } else {
        size_t b = blockIdx.x - NCODES;
        src = q + b * QD; dh = qh + b * QD; nrm = qsq + b;
    }
    int c = tid * 8;
    float4 t0 = *(const float4*)(src + c);
    float4 t1 = *(const float4*)(src + c + 4);
    float s = t0.x * t0.x + t0.y * t0.y + t0.z * t0.z + t0.w * t0.w
            + t1.x * t1.x + t1.y * t1.y + t1.z * t1.z + t1.w * t1.w;
    f16x8 h;
    h[0] = (_Float16)t0.x; h[1] = (_Float16)t0.y;
    h[2] = (_Float16)t0.z; h[3] = (_Float16)t0.w;
    h[4] = (_Float16)t1.x; h[5] = (_Float16)t1.y;
    h[6] = (_Float16)t1.z; h[7] = (_Float16)t1.w;
    *(f16x8*)(dh + c) = h;
    for (int off = 32; off > 0; off >>= 1) s += __shfl_down(s, off);
    if ((tid & 63) == 0) red[tid >> 6] = s;
    __syncthreads();
    if (tid == 0) *nrm = red[0] + red[1] + red[2] + red[3];
}

// ---------------- K1b: fallback prep (if ws too small for qh) ----------------
__global__ void k_prep_r17(const float* __restrict__ ctx, const float* __restrict__ q,
                           _Float16* __restrict__ gh, float* __restrict__ gsq,
                           float* __restrict__ qsq) {
    int tid = threadIdx.x;
    if (blockIdx.x < NCODES) {
        __shared__ float red[4];
        int n = blockIdx.x;
        float s = 0.f;
#pragma unroll
        for (int i = 0; i < 2; ++i) {
            int c = (tid + i * 256) * 4;
            float4 t = *(const float4*)(ctx + (size_t)n * QD + c);
            f16x4 h;
            h[0] = (_Float16)t.x; h[1] = (_Float16)t.y;
            h[2] = (_Float16)t.z; h[3] = (_Float16)t.w;
            *(f16x4*)(gh + (size_t)n * QD + c) = h;
            s += t.x * t.x + t.y * t.y + t.z * t.z + t.w * t.w;
        }
        for (int off = 32; off > 0; off >>= 1) s += __shfl_down(s, off);
        if ((tid & 63) == 0) red[tid >> 6] = s;
        __syncthreads();
        if (tid == 0) gsq[n] = red[0] + red[1] + red[2] + red[3];
    } else {
        int w = tid >> 6, lane = tid & 63;
        int b = (blockIdx.x - NCODES) * 4 + w;
        const float4* row = (const float4*)(q + (size_t)b * QD);
        float s = 0.f;
#pragma unroll
        for (int i = 0; i < 8; ++i) {
            float4 v = row[lane + i * 64];
            s += v.x * v.x + v.y * v.y + v.z * v.z + v.w * v.w;
        }
        for (int off = 32; off > 0; off >>= 1) s += __shfl_down(s, off);
        if (lane == 0) qsq[b] = s;
    }
}

// ---------------- K2a: 1-term fp16 GEMM, batch-2 staging (1 drain / 2 K-tiles) ------
// r18's 118us kernel with TWO sub-buffers per operand: stage both tiles (32
// gload_lds wave-instrs), ONE vmcnt drain, compute both (32 MFMA/wave). Barrier
// count halves vs r18 (64->32/block). Inner geometry byte-identical per sub-buffer
// (same [128][64] layout, swizzle, fragment reads). Occupancy unchanged: register-
// pinned at 2 blocks/CU; LDS 64KB x 2 blocks = 128KB <= 160KB.
// NOT r12's failed overlap-dbuf (no stage/compute interleave); m132's BK=128
// regression was occupancy-driven (3->2 blocks) -- does not apply here.
__launch_bounds__(256)
__global__ void k_dist_pre(const _Float16* __restrict__ qh, const _Float16* __restrict__ gh,
                           const float* __restrict__ gsq,
                           float* __restrict__ pval, int* __restrict__ pidx) {
    __shared__ _Float16 ah[2][128][64];
    __shared__ _Float16 bh[2][128][64];

    const int tid = threadIdx.x;
    const int lane = tid & 63, wid = tid >> 6;
    const int wr = wid >> 1, wc = wid & 1;
    // XCD-chunked mapping: 8 col-blocks of one row-tile dispatch-adjacent on one XCD.
    const int n0 = blockIdx.x;
    const int xcd = n0 & 7, j = n0 >> 3;
    const int col = j & 7, rowt = xcd * 16 + (j >> 3);
    const int colBase = col * 128, rowBase = rowt * 128;
    const int fr = lane & 15, kg = lane >> 4;

    // staging geometry (r5-proven): 8-row group, pre-XORed 16B granule
    const int srow = lane >> 3;
    const int gran = (lane & 7) ^ (lane >> 3);

    f32x4 acc[4][4];
#pragma unroll
    for (int m = 0; m < 4; ++m)
#pragma unroll
        for (int n = 0; n < 4; ++n) acc[m][n] = (f32x4)0.f;

    for (int kb = 0; kb < QD; kb += 128) {
        __syncthreads();   // prev compute done -> safe to overwrite both buffers
        // stage BOTH K-tiles (kb, kb+64) into sub-buffers 0/1
#pragma unroll
        for (int d = 0; d < 2; ++d) {
#pragma unroll
            for (int i = 0; i < 4; ++i) {
                int g = wid * 4 + i;
                size_t roff = (size_t)(rowBase + g * 8 + srow) * QD + kb + d * 64 + gran * 8;
                size_t coff = (size_t)(colBase + g * 8 + srow) * QD + kb + d * 64 + gran * 8;
                async_copy16(qh + roff, &ah[d][g * 8][0]);
                async_copy16(gh + coff, &bh[d][g * 8][0]);
            }
        }
        __syncthreads();   // single drain for both tiles

#pragma unroll
        for (int d = 0; d < 2; ++d) {
            const char* ahB = (const char*)&ah[d][0][0];
            const char* bhB = (const char*)&bh[d][0][0];
#pragma unroll
            for (int h = 0; h < 2; ++h) {
                f16x8 a_h[4], b_h[4];
#pragma unroll
                for (int m = 0; m < 4; ++m) {
                    int ar = wr * 64 + m * 16 + fr;
                    int off = ar * 128 + ((h * 64 + kg * 16) ^ ((ar & 7) << 4));
                    a_h[m] = *(const f16x8*)(ahB + off);
                }
#pragma unroll
                for (int n = 0; n < 4; ++n) {
                    int br = wc * 64 + n * 16 + fr;
                    int off = br * 128 + ((h * 64 + kg * 16) ^ ((br & 7) << 4));
                    b_h[n] = *(const f16x8*)(bhB + off);
                }
#pragma unroll
                for (int m = 0; m < 4; ++m)
#pragma unroll
                    for (int n = 0; n < 4; ++n)
                        acc[m][n] = __builtin_amdgcn_mfma_f32_16x16x32_f16(a_h[m], b_h[n], acc[m][n], 0, 0, 0);
            }
        }
    }

    // epilogue: d = gsq - 2*dot; per-row argmin (first-occurrence ties)
    float mv[4][4]; int mi[4][4];
#pragma unroll
    for (int m = 0; m < 4; ++m)
#pragma unroll
        for (int r = 0; r < 4; ++r) { mv[m][r] = FLT_MAX; mi[m][r] = 0x7fffffff; }
#pragma unroll
    for (int n = 0; n < 4; ++n) {
        int c = colBase + wc * 64 + n * 16 + fr;
        float gq = gsq[c];
#pragma unroll
        for (int m = 0; m < 4; ++m)
#pragma unroll
            for (int r = 0; r < 4; ++r) {
                float d = gq - 2.0f * acc[m][n][r];
                if (d < mv[m][r]) { mv[m][r] = d; mi[m][r] = c; }
            }
    }
#pragma unroll
    for (int off = 1; off < 16; off <<= 1) {
#pragma unroll
        for (int m = 0; m < 4; ++m)
#pragma unroll
            for (int r = 0; r < 4; ++r) {
                float ov = __shfl_xor(mv[m][r], off);
                int   oi = __shfl_xor(mi[m][r], off);
                if (ov < mv[m][r] || (ov == mv[m][r] && oi < mi[m][r])) { mv[m][r] = ov; mi[m][r] = oi; }
            }
    }
    if (fr == 0) {
        const size_t slot = (size_t)(col * 2 + wc) * BSZ;
#pragma unroll
        for (int m = 0; m < 4; ++m)
#pragma unroll
            for (int r = 0; r < 4; ++r) {
                int grow = rowBase + wr * 64 + m * 16 + kg * 4 + r;
                pval[slot + grow] = mv[m][r];
                pidx[slot + grow] = mi[m][r];
            }
    }
}

// ---------------- K2b: fallback GEMM (in-loop q cvt, r17 -- measured 145us) ---------
__launch_bounds__(256)
__global__ void k_dist_r17(const float* __restrict__ q, const _Float16* __restrict__ gh,
                           const float* __restrict__ gsq,
                           float* __restrict__ pval, int* __restrict__ pidx) {
    __shared__ _Float16 ah[128][64];
    __shared__ _Float16 bh[128][64];

    const int tid = threadIdx.x;
    const int lane = tid & 63, wid = tid >> 6;
    const int wr = wid >> 1, wc = wid & 1;
    const int n0 = blockIdx.x;
    const int xcd = n0 & 7, j = n0 >> 3;
    const int col = j & 7, rowt = xcd * 16 + (j >> 3);
    const int colBase = col * 128, rowBase = rowt * 128;
    const int fr = lane & 15, kg = lane >> 4;

    char* ahB = (char*)&ah[0][0];
    const char* bhB = (const char*)&bh[0][0];

    f32x4 acc[4][4];
#pragma unroll
    for (int m = 0; m < 4; ++m)
#pragma unroll
        for (int n = 0; n < 4; ++n) acc[m][n] = (f32x4)0.f;

    for (int kb = 0; kb < QD; kb += 64) {
        __syncthreads();
#pragma unroll
        for (int s = 0; s < 8; ++s) {
            int f = s * 256 + tid;
            int row = f >> 4, k4 = (f & 15) * 4;
            float4 t = *(const float4*)(q + (size_t)(rowBase + row) * QD + kb + k4);
            f16x4 h;
            h[0] = (_Float16)t.x; h[1] = (_Float16)t.y;
            h[2] = (_Float16)t.z; h[3] = (_Float16)t.w;
            int byt = (row * 128 + k4 * 2) ^ ((row & 7) << 4);
            *(f16x4*)(ahB + byt) = h;
        }
#pragma unroll
        for (int i = 0; i < 4; ++i) {
            int g = wid * 4 + i;
            int row = g * 8 + (lane >> 3);
            int gran = (lane & 7) ^ (lane >> 3);
            size_t goff = (size_t)(colBase + row) * QD + kb + gran * 8;
            async_copy16(gh + goff, &bh[g * 8][0]);
        }
        __syncthreads();

#pragma unroll
        for (int h = 0; h < 2; ++h) {
            f16x8 a_h[4], b_h[4];
#pragma unroll
            for (int m = 0; m < 4; ++m) {
                int ar = wr * 64 + m * 16 + fr;
                int off = ar * 128 + ((h * 64 + kg * 16) ^ ((ar & 7) << 4));
                a_h[m] = *(const f16x8*)(ahB + off);
            }
#pragma unroll
            for (int n = 0; n < 4; ++n) {
                int br = wc * 64 + n * 16 + fr;
                int off = br * 128 + ((h * 64 + kg * 16) ^ ((br & 7) << 4));
                b_h[n] = *(const f16x8*)(bhB + off);
            }
#pragma unroll
            for (int m = 0; m < 4; ++m)
#pragma unroll
                for (int n = 0; n < 4; ++n)
                    acc[m][n] = __builtin_amdgcn_mfma_f32_16x16x32_f16(a_h[m], b_h[n], acc[m][n], 0, 0, 0);
        }
    }

    float mv[4][4]; int mi[4][4];
#pragma unroll
    for (int m = 0; m < 4; ++m)
#pragma unroll
        for (int r = 0; r < 4; ++r) { mv[m][r] = FLT_MAX; mi[m][r] = 0x7fffffff; }
#pragma unroll
    for (int n = 0; n < 4; ++n) {
        int c = colBase + wc * 64 + n * 16 + fr;
        float gq = gsq[c];
#pragma unroll
        for (int m = 0; m < 4; ++m)
#pragma unroll
            for (int r = 0; r < 4; ++r) {
                float d = gq - 2.0f * acc[m][n][r];
                if (d < mv[m][r]) { mv[m][r] = d; mi[m][r] = c; }
            }
    }
#pragma unroll
    for (int off = 1; off < 16; off <<= 1) {
#pragma unroll
        for (int m = 0; m < 4; ++m)
#pragma unroll
            for (int r = 0; r < 4; ++r) {
                float ov = __shfl_xor(mv[m][r], off);
                int   oi = __shfl_xor(mi[m][r], off);
                if (ov < mv[m][r] || (ov == mv[m][r] && oi < mi[m][r])) { mv[m][r] = ov; mi[m][r] = oi; }
            }
    }
    if (fr == 0) {
        const size_t slot = (size_t)(col * 2 + wc) * BSZ;
#pragma unroll
        for (int m = 0; m < 4; ++m)
#pragma unroll
            for (int r = 0; r < 4; ++r) {
                int grow = rowBase + wr * 64 + m * 16 + kg * 4 + r;
                pval[slot + grow] = mv[m][r];
                pidx[slot + grow] = mi[m][r];
            }
    }
}

// ---------------- K3: merge 16 partials -> argmin + fused qld + fused chunk-hist ----
__global__ void k_merge(const float* __restrict__ pval, const int* __restrict__ pidx,
                        const float* __restrict__ qsq,
                        int* __restrict__ idx_out, float* __restrict__ qld,
                        int* __restrict__ chunkhist) {
    __shared__ int h[NCODES];
    int c = blockIdx.x, tid = threadIdx.x;
    int b = c * 256 + tid;
#pragma unroll
    for (int s = 0; s < 4; ++s) h[tid + s * 256] = 0;
    float bv = pval[b]; int bi = pidx[b];
    for (int y = 1; y < NCOLG; ++y) {
        float v = pval[(size_t)y * BSZ + b]; int ii = pidx[(size_t)y * BSZ + b];
        if (v < bv || (v == bv && ii < bi)) { bv = v; bi = ii; }
    }
    idx_out[b] = bi;
    qld[b] = (qsq[b] + bv) * (1.0f / (float)QD);
    __syncthreads();
    atomicAdd(&h[bi], 1);
    __syncthreads();
#pragma unroll
    for (int s = 0; s < 4; ++s) chunkhist[c * NCODES + tid + s * 256] = h[tid + s * 256];
}

// ---------------- K4: scan (counting sort) + fused ec ----------------
__global__ void k_scan(const int* __restrict__ chunkhist, int* __restrict__ base,
                       int* __restrict__ counts, int* __restrict__ offsets,
                       const float* __restrict__ ema_count, float* __restrict__ ec_out) {
    __shared__ int s[NCODES];
    __shared__ float e2[NCODES];
    int code = threadIdx.x;  // 1024 threads
    int run = 0;
    for (int c = 0; c < NCHUNK; ++c) {
        base[c * NCODES + code] = run;
        run += chunkhist[c * NCODES + code];
    }
    counts[code] = run;
    s[code] = run; __syncthreads();
    for (int off = 1; off < NCODES; off <<= 1) {
        int v = (code >= off) ? s[code - off] : 0;
        __syncthreads();
        s[code] += v; __syncthreads();
    }
    offsets[code] = s[code] - run;
    float er = 0.99f * ema_count[code] + one_minus_decay() * (float)run;
    e2[code] = er; __syncthreads();
    for (int off = 512; off > 0; off >>= 1) {
        if (code < off) e2[code] += e2[code + off];
        __syncthreads();
    }
    float n = e2[0];
    ec_out[code] = (er + 1e-5f) / (n + (float)(2048.0 * 1e-5)) * n;
}

__global__ void k_fill(const int* __restrict__ idx, const int* __restrict__ base,
                       const int* __restrict__ offsets, int* __restrict__ list) {
    __shared__ int sidx[256];
    int c = blockIdx.x, tid = threadIdx.x;
    int b = c * 256 + tid;
    int n = idx[b];
    sidx[tid] = n; __syncthreads();
    int rank = 0;
    for (int j = 0; j < tid; ++j) rank += (sidx[j] == n);
    list[offsets[n] + base[c * NCODES + n] + rank] = b;
}

// ---------------- K6a: q_hat segment-sum from fp16 qh (half the HBM read) -----------
// qhat error ~1e-3 absolute -> x0.01/ec ~1e-5 in outputs (flip-dominated absmax
// unchanged). Fixed summation order -> deterministic.
__global__ void k_qhat_h(const _Float16* __restrict__ qh, const int* __restrict__ counts,
                         const int* __restrict__ offsets, const int* __restrict__ list,
                         float* __restrict__ qhat) {
    int n = blockIdx.x;
    int col = blockIdx.y * 256 + threadIdx.x;
    int cnt = counts[n];
    const int* lp = list + offsets[n];
    float a0 = 0.f, a1 = 0.f, a2 = 0.f, a3 = 0.f, a4 = 0.f, a5 = 0.f, a6 = 0.f, a7 = 0.f;
    int i = 0;
    for (; i + 8 <= cnt; i += 8) {
        int b0 = lp[i], b1 = lp[i + 1], b2 = lp[i + 2], b3 = lp[i + 3];
        int b4 = lp[i + 4], b5 = lp[i + 5], b6 = lp[i + 6], b7 = lp[i + 7];
        a0 += (float)qh[(size_t)b0 * QD + col]; a1 += (float)qh[(size_t)b1 * QD + col];
        a2 += (float)qh[(size_t)b2 * QD + col]; a3 += (float)qh[(size_t)b3 * QD + col];
        a4 += (float)qh[(size_t)b4 * QD + col]; a5 += (float)qh[(size_t)b5 * QD + col];
        a6 += (float)qh[(size_t)b6 * QD + col]; a7 += (float)qh[(size_t)b7 * QD + col];
    }
    for (; i < cnt; ++i) a0 += (float)qh[(size_t)lp[i] * QD + col];
    float r = ((a0 + a1) + (a2 + a3)) + ((a4 + a5) + (a6 + a7));
    qhat[(size_t)n * QD + col] = r;
}

// ---------------- K6b: fallback q_hat from fp32 q ----------------
__global__ void k_qhat_f(const float* __restrict__ q, const int* __restrict__ counts,
                         const int* __restrict__ offsets, const int* __restrict__ list,
                         float* __restrict__ qhat) {
    int n = blockIdx.x;
    int col = blockIdx.y * 256 + threadIdx.x;
    int cnt = counts[n];
    const int* lp = list + offsets[n];
    float a0 = 0.f, a1 = 0.f, a2 = 0.f, a3 = 0.f, a4 = 0.f, a5 = 0.f, a6 = 0.f, a7 = 0.f;
    int i = 0;
    for (; i + 8 <= cnt; i += 8) {
        int b0 = lp[i], b1 = lp[i + 1], b2 = lp[i + 2], b3 = lp[i + 3];
        int b4 = lp[i + 4], b5 = lp[i + 5], b6 = lp[i + 6], b7 = lp[i + 7];
        a0 += q[(size_t)b0 * QD + col]; a1 += q[(size_t)b1 * QD + col];
        a2 += q[(size_t)b2 * QD + col]; a3 += q[(size_t)b3 * QD + col];
        a4 += q[(size_t)b4 * QD + col]; a5 += q[(size_t)b5 * QD + col];
        a6 += q[(size_t)b6 * QD + col]; a7 += q[(size_t)b7 * QD + col];
    }
    for (; i < cnt; ++i) a0 += q[(size_t)lp[i] * QD + col];
    float r = ((a0 + a1) + (a2 + a3)) + ((a4 + a5) + (a6 + a7));
    qhat[(size_t)n * QD + col] = r;
}

// ---------------- K8: finalize edw / context_new / out_context ----------------
// qhat aliases outctx_out (same-thread read-then-write) -> no __restrict__ on those.
__global__ void k_fin(const float* __restrict__ ema_dw, const float* __restrict__ ec,
                      const float* qhat, float* edw_out, float* ctxnew_out,
                      float* outctx_out) {
    size_t i = ((size_t)blockIdx.x * 256 + threadIdx.x) * 8;
    int n = (int)(i >> 11);
    float e = ec[n];
    float om = one_minus_decay();
#pragma unroll
    for (int h = 0; h < 2; ++h) {
        float4 dw = *(const float4*)(ema_dw + i + h * 4);
        float4 qh = *(const float4*)(qhat + i + h * 4);
        float4 ed, cn;
        ed.x = 0.99f * dw.x + om * qh.x; ed.y = 0.99f * dw.y + om * qh.y;
        ed.z = 0.99f * dw.z + om * qh.z; ed.w = 0.99f * dw.w + om * qh.w;
        cn.x = ed.x / e; cn.y = ed.y / e; cn.z = ed.z / e; cn.w = ed.w / e;
        *(float4*)(edw_out + i + h * 4) = ed;
        *(float4*)(ctxnew_out + i + h * 4) = cn;
        *(float4*)(outctx_out + i + h * 4) = cn;
    }
}

extern "C" void kernel_launch(void* const* d_in, const int* in_sizes, int n_in,
                              void* d_out, int out_size, void* d_ws, size_t ws_size,
                              hipStream_t stream) {
    const float* q         = (const float*)d_in[0];
    const float* ctx       = (const float*)d_in[1];
    const float* ema_count = (const float*)d_in[2];
    const float* ema_dw    = (const float*)d_in[3];

    float* out = (float*)d_out;
    float* o_qld    = out;                              // 16384
    float* o_outctx = out + BSZ;                        // 2097152
    float* o_ec     = o_outctx + (size_t)NCODES * QD;   // 1024
    float* o_edw    = o_ec + NCODES;                    // 2097152
    float* o_ctxnew = o_edw + (size_t)NCODES * QD;      // 2097152

    char* w = (char*)d_ws;
    float* ws_gsq   = (float*)w;                        // 1024 f
    int* ws_idx     = (int*)(w + 4096);                 // 16384 i
    int* ws_counts  = (int*)(w + 4096 + 65536);         // 1024 i
    int* ws_offsets = ws_counts + NCODES;               // 1024 i
    int* ws_list    = ws_offsets + NCODES;              // 16384 i

    // qh pre-split scratch (64 MB) at ws + 1MB, if available
    const size_t presplit_need = (size_t)1048576 + (size_t)BSZ * QD * sizeof(_Float16);
    const bool use_pre = (ws_size >= presplit_need);
    _Float16* qh = (_Float16*)(w + 1048576);

    // scratch carved from not-yet-written d_out regions:
    _Float16* gh = (_Float16*)o_ctxnew;                 // 4MB (dead after k_dist)
    float* pval  = o_edw;                               // 1MB (dead after k_merge)
    int*   pidx  = (int*)(o_edw + (size_t)NCOLG * BSZ); // 1MB
    float* qsq   = o_edw + (size_t)2 * NCOLG * BSZ;     // 64KB (dead after k_merge)
    int* chunkhist = (int*)o_outctx;                    // 256KB (dead after k_scan)
    int* basep     = chunkhist + NCHUNK * NCODES;       // 256KB (dead after k_fill)
    float* qhat    = o_outctx;                          // 8MB (finalized by k_fin)

    if (use_pre) {
        k_prep_all<<<NCODES + BSZ, 256, 0, stream>>>(ctx, q, gh, ws_gsq, qh, qsq);
        k_dist_pre<<<1024, 256, 0, stream>>>(qh, gh, ws_gsq, pval, pidx);
    } else {
        k_prep_r17<<<NCODES + BSZ / 4, 256, 0, stream>>>(ctx, q, gh, ws_gsq, qsq);
        k_dist_r17<<<1024, 256, 0, stream>>>(q, gh, ws_gsq, pval, pidx);
    }
    k_merge <<<NCHUNK, 256, 0, stream>>>(pval, pidx, qsq, ws_idx, o_qld, chunkhist);
    k_scan  <<<1, 1024, 0, stream>>>(chunkhist, basep, ws_counts, ws_offsets, ema_count, o_ec);
    k_fill  <<<NCHUNK, 256, 0, stream>>>(ws_idx, basep, ws_offsets, ws_list);
    if (use_pre) {
        k_qhat_h<<<dim3(NCODES, 8), 256, 0, stream>>>(qh, ws_counts, ws_offsets, ws_list, qhat);
    } else {
        k_qhat_f<<<dim3(NCODES, 8), 256, 0, stream>>>(q, ws_counts, ws_offsets, ws_list, qhat);
    }
    k_fin   <<<NCODES * QD / 2048, 256, 0, stream>>>(ema_dw, o_ec, qhat,
                                                     o_edw, o_ctxnew, o_outctx);
}

// Round 20
// 199.701 us; speedup vs baseline: 1.6862x; 1.0062x over previous
//
#include <hip/hip_runtime.h>
#include <hip/hip_bf16.h>
#include <float.h>

#define BSZ 16384
#define NCODES 1024
#define QD 2048
#define NCHUNK 64   // BSZ / 256
#define NCOLG 16    // 8 col-blocks x 2 wc-waves

typedef _Float16 f16x8 __attribute__((ext_vector_type(8)));
typedef _Float16 f16x4 __attribute__((ext_vector_type(4)));
typedef float f32x4 __attribute__((ext_vector_type(4)));

static __device__ __forceinline__ float one_minus_decay() { return (float)(1.0 - 0.99); }

static __device__ __forceinline__ void async_copy16(const void* src, void* lds) {
    __builtin_amdgcn_global_load_lds((const __attribute__((address_space(1))) void*)src,
                                     (__attribute__((address_space(3))) void*)lds, 16, 0, 0);
}

// ---------------- K1a: unified prep -- EVERY row (ctx then q) -> fp16 hi + norm ----
__global__ void k_prep_all(const float* __restrict__ ctx, const float* __restrict__ q,
                           _Float16* __restrict__ gh, float* __restrict__ gsq,
                           _Float16* __restrict__ qh, float* __restrict__ qsq) {
    __shared__ float red[4];
    int tid = threadIdx.x;
    const float* src; _Float16* dh; float* nrm;
    if (blockIdx.x < NCODES) {
        size_t n = blockIdx.x;
        src = ctx + n * QD; dh = gh + n * QD; nrm = gsq + n;
    } else {
        size_t b = blockIdx.x - NCODES;
        src = q + b * QD; dh = qh + b * QD; nrm = qsq + b;
    }
    int c = tid * 8;
    float4 t0 = *(const float4*)(src + c);
    float4 t1 = *(const float4*)(src + c + 4);
    float s = t0.x * t0.x + t0.y * t0.y + t0.z * t0.z + t0.w * t0.w
            + t1.x * t1.x + t1.y * t1.y + t1.z * t1.z + t1.w * t1.w;
    f16x8 h;
    h[0] = (_Float16)t0.x; h[1] = (_Float16)t0.y;
    h[2] = (_Float16)t0.z; h[3] = (_Float16)t0.w;
    h[4] = (_Float16)t1.x; h[5] = (_Float16)t1.y;
    h[6] = (_Float16)t1.z; h[7] = (_Float16)t1.w;
    *(f16x8*)(dh + c) = h;
    for (int off = 32; off > 0; off >>= 1) s += __shfl_down(s, off);
    if ((tid & 63) == 0) red[tid >> 6] = s;
    __syncthreads();
    if (tid == 0) *nrm = red[0] + red[1] + red[2] + red[3];
}

// ---------------- K1b: fallback prep (if ws too small for qh) ----------------
__global__ void k_prep_r17(const float* __restrict__ ctx, const float* __restrict__ q,
                           _Float16* __restrict__ gh, float* __restrict__ gsq,
                           float* __restrict__ qsq) {
    int tid = threadIdx.x;
    if (blockIdx.x < NCODES) {
        __shared__ float red[4];
        int n = blockIdx.x;
        float s = 0.f;
#pragma unroll
        for (int i = 0; i < 2; ++i) {
            int c = (tid + i * 256) * 4;
            float4 t = *(const float4*)(ctx + (size_t)n * QD + c);
            f16x4 h;
            h[0] = (_Float16)t.x; h[1] = (_Float16)t.y;
            h[2] = (_Float16)t.z; h[3] = (_Float16)t.w;
            *(f16x4*)(gh + (size_t)n * QD + c) = h;
            s += t.x * t.x + t.y * t.y + t.z * t.z + t.w * t.w;
        }
        for (int off = 32; off > 0; off >>= 1) s += __shfl_down(s, off);
        if ((tid & 63) == 0) red[tid >> 6] = s;
        __syncthreads();
        if (tid == 0) gsq[n] = red[0] + red[1] + red[2] + red[3];
    } else {
        int w = tid >> 6, lane = tid & 63;
        int b = (blockIdx.x - NCODES) * 4 + w;
        const float4* row = (const float4*)(q + (size_t)b * QD);
        float s = 0.f;
#pragma unroll
        for (int i = 0; i < 8; ++i) {
            float4 v = row[lane + i * 64];
            s += v.x * v.x + v.y * v.y + v.z * v.z + v.w * v.w;
        }
        for (int off = 32; off > 0; off >>= 1) s += __shfl_down(s, off);
        if (lane == 0) qsq[b] = s;
    }
}

// ---------------- K2a: 1-term fp16 GEMM, counted-vmcnt software pipeline ------------
// r19's batch-2 (108us, ~50% drain-stall) restructured as a 1-tile-deep pipeline
// (T3/T4 minimum form): per 64-wide K-tile t:
//   s_waitcnt vmcnt(8)   <- waits tile-t's own 8 gload_lds; tile-(t+1)'s stay in flight
//   s_barrier            <- all waves' tile-t loads landed -> buf[t&1] ready
//   32 MFMA on buf[t&1]
//   s_barrier            <- all waves done READING buf[t&1]
//   issue tile t+2 -> buf[t&1]  (8 gload_lds; has tile-(t+1)'s full compute to land)
// Never drains vmcnt to 0 in the loop (peeled last tile uses vmcnt(0)).
// LDS 2x32KB = 64KB; occupancy unchanged (register-pinned 2 blocks/CU).
// Numerics byte-identical to r19 -> absmax must stay 0.05090332 (race detector).
__launch_bounds__(256)
__global__ void k_dist_pre(const _Float16* __restrict__ qh, const _Float16* __restrict__ gh,
                           const float* __restrict__ gsq,
                           float* __restrict__ pval, int* __restrict__ pidx) {
    __shared__ _Float16 ah[2][128][64];
    __shared__ _Float16 bh[2][128][64];

    const int tid = threadIdx.x;
    const int lane = tid & 63, wid = tid >> 6;
    const int wr = wid >> 1, wc = wid & 1;
    // XCD-chunked mapping: 8 col-blocks of one row-tile dispatch-adjacent on one XCD.
    const int n0 = blockIdx.x;
    const int xcd = n0 & 7, j = n0 >> 3;
    const int col = j & 7, rowt = xcd * 16 + (j >> 3);
    const int colBase = col * 128, rowBase = rowt * 128;
    const int fr = lane & 15, kg = lane >> 4;

    // staging geometry (r5-proven): 8-row group, pre-XORed 16B granule
    const int srow = lane >> 3;
    const int gran = (lane & 7) ^ (lane >> 3);

    f32x4 acc[4][4];
#pragma unroll
    for (int m = 0; m < 4; ++m)
#pragma unroll
        for (int n = 0; n < 4; ++n) acc[m][n] = (f32x4)0.f;

#define STAGE_TILE(KB, BUF)                                                           \
    {                                                                                 \
        _Pragma("unroll")                                                             \
        for (int i_ = 0; i_ < 4; ++i_) {                                              \
            int g_ = wid * 4 + i_;                                                    \
            size_t ro_ = (size_t)(rowBase + g_ * 8 + srow) * QD + (KB) + gran * 8;    \
            size_t co_ = (size_t)(colBase + g_ * 8 + srow) * QD + (KB) + gran * 8;    \
            async_copy16(qh + ro_, &ah[BUF][g_ * 8][0]);                              \
            async_copy16(gh + co_, &bh[BUF][g_ * 8][0]);                              \
        }                                                                             \
    }

#define COMPUTE_TILE(BUF)                                                             \
    {                                                                                 \
        const char* ahB_ = (const char*)&ah[BUF][0][0];                               \
        const char* bhB_ = (const char*)&bh[BUF][0][0];                               \
        _Pragma("unroll")                                                             \
        for (int h_ = 0; h_ < 2; ++h_) {                                              \
            f16x8 a_h[4], b_h[4];                                                     \
            _Pragma("unroll")                                                         \
            for (int m_ = 0; m_ < 4; ++m_) {                                          \
                int ar_ = wr * 64 + m_ * 16 + fr;                                     \
                int off_ = ar_ * 128 + ((h_ * 64 + kg * 16) ^ ((ar_ & 7) << 4));      \
                a_h[m_] = *(const f16x8*)(ahB_ + off_);                               \
            }                                                                         \
            _Pragma("unroll")                                                         \
            for (int n_ = 0; n_ < 4; ++n_) {                                          \
                int br_ = wc * 64 + n_ * 16 + fr;                                     \
                int off_ = br_ * 128 + ((h_ * 64 + kg * 16) ^ ((br_ & 7) << 4));      \
                b_h[n_] = *(const f16x8*)(bhB_ + off_);                               \
            }                                                                         \
            _Pragma("unroll")                                                         \
            for (int m_ = 0; m_ < 4; ++m_)                                            \
                _Pragma("unroll")                                                     \
                for (int n_ = 0; n_ < 4; ++n_)                                        \
                    acc[m_][n_] = __builtin_amdgcn_mfma_f32_16x16x32_f16(             \
                        a_h[m_], b_h[n_], acc[m_][n_], 0, 0, 0);                      \
        }                                                                             \
    }

    // prologue: tiles 0 and 1 in flight
    STAGE_TILE(0, 0);
    STAGE_TILE(64, 1);

    for (int t = 0; t < 31; ++t) {
        asm volatile("s_waitcnt vmcnt(8)" ::: "memory");   // tile-t's loads landed
        __builtin_amdgcn_s_barrier();
        COMPUTE_TILE(t & 1);
        __builtin_amdgcn_s_barrier();                      // all waves done reading
        if (t < 30) STAGE_TILE((t + 2) * 64, t & 1);       // prefetch 2 ahead
    }
    // peeled last tile (t = 31): only its own 8 loads remain outstanding
    asm volatile("s_waitcnt vmcnt(0)" ::: "memory");
    __builtin_amdgcn_s_barrier();
    COMPUTE_TILE(1);

#undef STAGE_TILE
#undef COMPUTE_TILE

    // epilogue: d = gsq - 2*dot; per-row argmin (first-occurrence ties)
    float mv[4][4]; int mi[4][4];
#pragma unroll
    for (int m = 0; m < 4; ++m)
#pragma unroll
        for (int r = 0; r < 4; ++r) { mv[m][r] = FLT_MAX; mi[m][r] = 0x7fffffff; }
#pragma unroll
    for (int n = 0; n < 4; ++n) {
        int c = colBase + wc * 64 + n * 16 + fr;
        float gq = gsq[c];
#pragma unroll
        for (int m = 0; m < 4; ++m)
#pragma unroll
            for (int r = 0; r < 4; ++r) {
                float d = gq - 2.0f * acc[m][n][r];
                if (d < mv[m][r]) { mv[m][r] = d; mi[m][r] = c; }
            }
    }
#pragma unroll
    for (int off = 1; off < 16; off <<= 1) {
#pragma unroll
        for (int m = 0; m < 4; ++m)
#pragma unroll
            for (int r = 0; r < 4; ++r) {
                float ov = __shfl_xor(mv[m][r], off);
                int   oi = __shfl_xor(mi[m][r], off);
                if (ov < mv[m][r] || (ov == mv[m][r] && oi < mi[m][r])) { mv[m][r] = ov; mi[m][r] = oi; }
            }
    }
    if (fr == 0) {
        const size_t slot = (size_t)(col * 2 + wc) * BSZ;
#pragma unroll
        for (int m = 0; m < 4; ++m)
#pragma unroll
            for (int r = 0; r < 4; ++r) {
                int grow = rowBase + wr * 64 + m * 16 + kg * 4 + r;
                pval[slot + grow] = mv[m][r];
                pidx[slot + grow] = mi[m][r];
            }
    }
}

// ---------------- K2b: fallback GEMM (in-loop q cvt, r17 -- measured 145us) ---------
__launch_bounds__(256)
__global__ void k_dist_r17(const float* __restrict__ q, const _Float16* __restrict__ gh,
                           const float* __restrict__ gsq,
                           float* __restrict__ pval, int* __restrict__ pidx) {
    __shared__ _Float16 ah[128][64];
    __shared__ _Float16 bh[128][64];

    const int tid = threadIdx.x;
    const int lane = tid & 63, wid = tid >> 6;
    const int wr = wid >> 1, wc = wid & 1;
    const int n0 = blockIdx.x;
    const int xcd = n0 & 7, j = n0 >> 3;
    const int col = j & 7, rowt = xcd * 16 + (j >> 3);
    const int colBase = col * 128, rowBase = rowt * 128;
    const int fr = lane & 15, kg = lane >> 4;

    char* ahB = (char*)&ah[0][0];
    const char* bhB = (const char*)&bh[0][0];

    f32x4 acc[4][4];
#pragma unroll
    for (int m = 0; m < 4; ++m)
#pragma unroll
        for (int n = 0; n < 4; ++n) acc[m][n] = (f32x4)0.f;

    for (int kb = 0; kb < QD; kb += 64) {
        __syncthreads();
#pragma unroll
        for (int s = 0; s < 8; ++s) {
            int f = s * 256 + tid;
            int row = f >> 4, k4 = (f & 15) * 4;
            float4 t = *(const float4*)(q + (size_t)(rowBase + row) * QD + kb + k4);
            f16x4 h;
            h[0] = (_Float16)t.x; h[1] = (_Float16)t.y;
            h[2] = (_Float16)t.z; h[3] = (_Float16)t.w;
            int byt = (row * 128 + k4 * 2) ^ ((row & 7) << 4);
            *(f16x4*)(ahB + byt) = h;
        }
#pragma unroll
        for (int i = 0; i < 4; ++i) {
            int g = wid * 4 + i;
            int row = g * 8 + (lane >> 3);
            int gran = (lane & 7) ^ (lane >> 3);
            size_t goff = (size_t)(colBase + row) * QD + kb + gran * 8;
            async_copy16(gh + goff, &bh[g * 8][0]);
        }
        __syncthreads();

#pragma unroll
        for (int h = 0; h < 2; ++h) {
            f16x8 a_h[4], b_h[4];
#pragma unroll
            for (int m = 0; m < 4; ++m) {
                int ar = wr * 64 + m * 16 + fr;
                int off = ar * 128 + ((h * 64 + kg * 16) ^ ((ar & 7) << 4));
                a_h[m] = *(const f16x8*)(ahB + off);
            }
#pragma unroll
            for (int n = 0; n < 4; ++n) {
                int br = wc * 64 + n * 16 + fr;
                int off = br * 128 + ((h * 64 + kg * 16) ^ ((br & 7) << 4));
                b_h[n] = *(const f16x8*)(bhB + off);
            }
#pragma unroll
            for (int m = 0; m < 4; ++m)
#pragma unroll
                for (int n = 0; n < 4; ++n)
                    acc[m][n] = __builtin_amdgcn_mfma_f32_16x16x32_f16(a_h[m], b_h[n], acc[m][n], 0, 0, 0);
        }
    }

    float mv[4][4]; int mi[4][4];
#pragma unroll
    for (int m = 0; m < 4; ++m)
#pragma unroll
        for (int r = 0; r < 4; ++r) { mv[m][r] = FLT_MAX; mi[m][r] = 0x7fffffff; }
#pragma unroll
    for (int n = 0; n < 4; ++n) {
        int c = colBase + wc * 64 + n * 16 + fr;
        float gq = gsq[c];
#pragma unroll
        for (int m = 0; m < 4; ++m)
#pragma unroll
            for (int r = 0; r < 4; ++r) {
                float d = gq - 2.0f * acc[m][n][r];
                if (d < mv[m][r]) { mv[m][r] = d; mi[m][r] = c; }
            }
    }
#pragma unroll
    for (int off = 1; off < 16; off <<= 1) {
#pragma unroll
        for (int m = 0; m < 4; ++m)
#pragma unroll
            for (int r = 0; r < 4; ++r) {
                float ov = __shfl_xor(mv[m][r], off);
                int   oi = __shfl_xor(mi[m][r], off);
                if (ov < mv[m][r] || (ov == mv[m][r] && oi < mi[m][r])) { mv[m][r] = ov; mi[m][r] = oi; }
            }
    }
    if (fr == 0) {
        const size_t slot = (size_t)(col * 2 + wc) * BSZ;
#pragma unroll
        for (int m = 0; m < 4; ++m)
#pragma unroll
            for (int r = 0; r < 4; ++r) {
                int grow = rowBase + wr * 64 + m * 16 + kg * 4 + r;
                pval[slot + grow] = mv[m][r];
                pidx[slot + grow] = mi[m][r];
            }
    }
}

// ---------------- K3: merge 16 partials -> argmin + fused qld + fused chunk-hist ----
__global__ void k_merge(const float* __restrict__ pval, const int* __restrict__ pidx,
                        const float* __restrict__ qsq,
                        int* __restrict__ idx_out, float* __restrict__ qld,
                        int* __restrict__ chunkhist) {
    __shared__ int h[NCODES];
    int c = blockIdx.x, tid = threadIdx.x;
    int b = c * 256 + tid;
#pragma unroll
    for (int s = 0; s < 4; ++s) h[tid + s * 256] = 0;
    float bv = pval[b]; int bi = pidx[b];
    for (int y = 1; y < NCOLG; ++y) {
        float v = pval[(size_t)y * BSZ + b]; int ii = pidx[(size_t)y * BSZ + b];
        if (v < bv || (v == bv && ii < bi)) { bv = v; bi = ii; }
    }
    idx_out[b] = bi;
    qld[b] = (qsq[b] + bv) * (1.0f / (float)QD);
    __syncthreads();
    atomicAdd(&h[bi], 1);
    __syncthreads();
#pragma unroll
    for (int s = 0; s < 4; ++s) chunkhist[c * NCODES + tid + s * 256] = h[tid + s * 256];
}

// ---------------- K4: scan (counting sort) + fused ec ----------------
__global__ void k_scan(const int* __restrict__ chunkhist, int* __restrict__ base,
                       int* __restrict__ counts, int* __restrict__ offsets,
                       const float* __restrict__ ema_count, float* __restrict__ ec_out) {
    __shared__ int s[NCODES];
    __shared__ float e2[NCODES];
    int code = threadIdx.x;  // 1024 threads
    int run = 0;
    for (int c = 0; c < NCHUNK; ++c) {
        base[c * NCODES + code] = run;
        run += chunkhist[c * NCODES + code];
    }
    counts[code] = run;
    s[code] = run; __syncthreads();
    for (int off = 1; off < NCODES; off <<= 1) {
        int v = (code >= off) ? s[code - off] : 0;
        __syncthreads();
        s[code] += v; __syncthreads();
    }
    offsets[code] = s[code] - run;
    float er = 0.99f * ema_count[code] + one_minus_decay() * (float)run;
    e2[code] = er; __syncthreads();
    for (int off = 512; off > 0; off >>= 1) {
        if (code < off) e2[code] += e2[code + off];
        __syncthreads();
    }
    float n = e2[0];
    ec_out[code] = (er + 1e-5f) / (n + (float)(2048.0 * 1e-5)) * n;
}

__global__ void k_fill(const int* __restrict__ idx, const int* __restrict__ base,
                       const int* __restrict__ offsets, int* __restrict__ list) {
    __shared__ int sidx[256];
    int c = blockIdx.x, tid = threadIdx.x;
    int b = c * 256 + tid;
    int n = idx[b];
    sidx[tid] = n; __syncthreads();
    int rank = 0;
    for (int j = 0; j < tid; ++j) rank += (sidx[j] == n);
    list[offsets[n] + base[c * NCODES + n] + rank] = b;
}

// ---------------- K6a: q_hat segment-sum from fp16 qh (half the HBM read) -----------
__global__ void k_qhat_h(const _Float16* __restrict__ qh, const int* __restrict__ counts,
                         const int* __restrict__ offsets, const int* __restrict__ list,
                         float* __restrict__ qhat) {
    int n = blockIdx.x;
    int col = blockIdx.y * 256 + threadIdx.x;
    int cnt = counts[n];
    const int* lp = list + offsets[n];
    float a0 = 0.f, a1 = 0.f, a2 = 0.f, a3 = 0.f, a4 = 0.f, a5 = 0.f, a6 = 0.f, a7 = 0.f;
    int i = 0;
    for (; i + 8 <= cnt; i += 8) {
        int b0 = lp[i], b1 = lp[i + 1], b2 = lp[i + 2], b3 = lp[i + 3];
        int b4 = lp[i + 4], b5 = lp[i + 5], b6 = lp[i + 6], b7 = lp[i + 7];
        a0 += (float)qh[(size_t)b0 * QD + col]; a1 += (float)qh[(size_t)b1 * QD + col];
        a2 += (float)qh[(size_t)b2 * QD + col]; a3 += (float)qh[(size_t)b3 * QD + col];
        a4 += (float)qh[(size_t)b4 * QD + col]; a5 += (float)qh[(size_t)b5 * QD + col];
        a6 += (float)qh[(size_t)b6 * QD + col]; a7 += (float)qh[(size_t)b7 * QD + col];
    }
    for (; i < cnt; ++i) a0 += (float)qh[(size_t)lp[i] * QD + col];
    float r = ((a0 + a1) + (a2 + a3)) + ((a4 + a5) + (a6 + a7));
    qhat[(size_t)n * QD + col] = r;
}

// ---------------- K6b: fallback q_hat from fp32 q ----------------
__global__ void k_qhat_f(const float* __restrict__ q, const int* __restrict__ counts,
                         const int* __restrict__ offsets, const int* __restrict__ list,
                         float* __restrict__ qhat) {
    int n = blockIdx.x;
    int col = blockIdx.y * 256 + threadIdx.x;
    int cnt = counts[n];
    const int* lp = list + offsets[n];
    float a0 = 0.f, a1 = 0.f, a2 = 0.f, a3 = 0.f, a4 = 0.f, a5 = 0.f, a6 = 0.f, a7 = 0.f;
    int i = 0;
    for (; i + 8 <= cnt; i += 8) {
        int b0 = lp[i], b1 = lp[i + 1], b2 = lp[i + 2], b3 = lp[i + 3];
        int b4 = lp[i + 4], b5 = lp[i + 5], b6 = lp[i + 6], b7 = lp[i + 7];
        a0 += q[(size_t)b0 * QD + col]; a1 += q[(size_t)b1 * QD + col];
        a2 += q[(size_t)b2 * QD + col]; a3 += q[(size_t)b3 * QD + col];
        a4 += q[(size_t)b4 * QD + col]; a5 += q[(size_t)b5 * QD + col];
        a6 += q[(size_t)b6 * QD + col]; a7 += q[(size_t)b7 * QD + col];
    }
    for (; i < cnt; ++i) a0 += q[(size_t)lp[i] * QD + col];
    float r = ((a0 + a1) + (a2 + a3)) + ((a4 + a5) + (a6 + a7));
    qhat[(size_t)n * QD + col] = r;
}

// ---------------- K8: finalize edw / context_new / out_context ----------------
__global__ void k_fin(const float* __restrict__ ema_dw, const float* __restrict__ ec,
                      const float* qhat, float* edw_out, float* ctxnew_out,
                      float* outctx_out) {
    size_t i = ((size_t)blockIdx.x * 256 + threadIdx.x) * 8;
    int n = (int)(i >> 11);
    float e = ec[n];
    float om = one_minus_decay();
#pragma unroll
    for (int h = 0; h < 2; ++h) {
        float4 dw = *(const float4*)(ema_dw + i + h * 4);
        float4 qh = *(const float4*)(qhat + i + h * 4);
        float4 ed, cn;
        ed.x = 0.99f * dw.x + om * qh.x; ed.y = 0.99f * dw.y + om * qh.y;
        ed.z = 0.99f * dw.z + om * qh.z; ed.w = 0.99f * dw.w + om * qh.w;
        cn.x = ed.x / e; cn.y = ed.y / e; cn.z = ed.z / e; cn.w = ed.w / e;
        *(float4*)(edw_out + i + h * 4) = ed;
        *(float4*)(ctxnew_out + i + h * 4) = cn;
        *(float4*)(outctx_out + i + h * 4) = cn;
    }
}

extern "C" void kernel_launch(void* const* d_in, const int* in_sizes, int n_in,
                              void* d_out, int out_size, void* d_ws, size_t ws_size,
                              hipStream_t stream) {
    const float* q         = (const float*)d_in[0];
    const float* ctx       = (const float*)d_in[1];
    const float* ema_count = (const float*)d_in[2];
    const float* ema_dw    = (const float*)d_in[3];

    float* out = (float*)d_out;
    float* o_qld    = out;                              // 16384
    float* o_outctx = out + BSZ;                        // 2097152
    float* o_ec     = o_outctx + (size_t)NCODES * QD;   // 1024
    float* o_edw    = o_ec + NCODES;                    // 2097152
    float* o_ctxnew = o_edw + (size_t)NCODES * QD;      // 2097152

    char* w = (char*)d_ws;
    float* ws_gsq   = (float*)w;                        // 1024 f
    int* ws_idx     = (int*)(w + 4096);                 // 16384 i
    int* ws_counts  = (int*)(w + 4096 + 65536);         // 1024 i
    int* ws_offsets = ws_counts + NCODES;               // 1024 i
    int* ws_list    = ws_offsets + NCODES;              // 16384 i

    // qh pre-split scratch (64 MB) at ws + 1MB, if available
    const size_t presplit_need = (size_t)1048576 + (size_t)BSZ * QD * sizeof(_Float16);
    const bool use_pre = (ws_size >= presplit_need);
    _Float16* qh = (_Float16*)(w + 1048576);

    // scratch carved from not-yet-written d_out regions:
    _Float16* gh = (_Float16*)o_ctxnew;                 // 4MB (dead after k_dist)
    float* pval  = o_edw;                               // 1MB (dead after k_merge)
    int*   pidx  = (int*)(o_edw + (size_t)NCOLG * BSZ); // 1MB
    float* qsq   = o_edw + (size_t)2 * NCOLG * BSZ;     // 64KB (dead after k_merge)
    int* chunkhist = (int*)o_outctx;                    // 256KB (dead after k_scan)
    int* basep     = chunkhist + NCHUNK * NCODES;       // 256KB (dead after k_fill)
    float* qhat    = o_outctx;                          // 8MB (finalized by k_fin)

    if (use_pre) {
        k_prep_all<<<NCODES + BSZ, 256, 0, stream>>>(ctx, q, gh, ws_gsq, qh, qsq);
        k_dist_pre<<<1024, 256, 0, stream>>>(qh, gh, ws_gsq, pval, pidx);
    } else {
        k_prep_r17<<<NCODES + BSZ / 4, 256, 0, stream>>>(ctx, q, gh, ws_gsq, qsq);
        k_dist_r17<<<1024, 256, 0, stream>>>(q, gh, ws_gsq, pval, pidx);
    }
    k_merge <<<NCHUNK, 256, 0, stream>>>(pval, pidx, qsq, ws_idx, o_qld, chunkhist);
    k_scan  <<<1, 1024, 0, stream>>>(chunkhist, basep, ws_counts, ws_offsets, ema_count, o_ec);
    k_fill  <<<NCHUNK, 256, 0, stream>>>(ws_idx, basep, ws_offsets, ws_list);
    if (use_pre) {
        k_qhat_h<<<dim3(NCODES, 8), 256, 0, stream>>>(qh, ws_counts, ws_offsets, ws_list, qhat);
    } else {
        k_qhat_f<<<dim3(NCODES, 8), 256, 0, stream>>>(q, ws_counts, ws_offsets, ws_list, qhat);
    }
    k_fin   <<<NCODES * QD / 2048, 256, 0, stream>>>(ema_dw, o_ec, qhat,
                                                     o_edw, o_ctxnew, o_outctx);
}